// Round 4
// baseline (1158.977 us; speedup 1.0000x reference)
//
#include <hip/hip_runtime.h>

#define HID 256
#define NDRUG 20000
#define NDIS 20000
#define NE 400000
#define NEL 100000
#define NLAYERS 4

typedef float f32x4 __attribute__((ext_vector_type(4)));
typedef short s16x8 __attribute__((ext_vector_type(8)));
typedef unsigned short ushort_t;
typedef unsigned int uint_t;

// ---- bf16 helpers (round-to-nearest-even) ----
__device__ __forceinline__ ushort_t f2bf(float f) {
    uint_t u = __float_as_uint(f);
    u += 0x7fffu + ((u >> 16) & 1u);
    return (ushort_t)(u >> 16);
}
__device__ __forceinline__ float bf2f(ushort_t h) {
    return __uint_as_float(((uint_t)h) << 16);
}

// ---- async global->LDS, 16B per lane; lptr must be wave-uniform base ----
__device__ __forceinline__ void gl_lds16(const void* g, void* l) {
    __builtin_amdgcn_global_load_lds(
        (const __attribute__((address_space(1))) void*)g,
        (__attribute__((address_space(3))) void*)l, 16, 0, 0);
}

// ---- m204 bijective XCD-chunked swizzle: contiguous tile range per XCD ----
__device__ __forceinline__ int xcd_swz(int orig, int nwg) {
    int q = nwg >> 3, r = nwg & 7;
    int x = orig & 7, i = orig >> 3;
    int start = (x < r) ? x * (q + 1) : r * (q + 1) + (x - r) * q;
    return start + i;
}

// ---------------- init: x_drug = drug_emb[id]; x_dis = dx@Wlin + b + dis_emb[id]
__global__ void k_init(const int* __restrict__ drug_id, const float* __restrict__ drug_emb,
                       const float* __restrict__ dx, const float* __restrict__ Wlin,
                       const float* __restrict__ blin, const int* __restrict__ dis_id,
                       const float* __restrict__ dis_emb,
                       ushort_t* __restrict__ xh_drug, ushort_t* __restrict__ xl_drug,
                       ushort_t* __restrict__ xh_dis, ushort_t* __restrict__ xl_dis)
{
    int n = blockIdx.x; int h = threadIdx.x;
    size_t o = (size_t)n * HID + h;
    float vd = drug_emb[(size_t)drug_id[n] * HID + h];
    ushort_t hd = f2bf(vd);
    xh_drug[o] = hd;
    xl_drug[o] = f2bf(vd - bf2f(hd));

    __shared__ float xr[10];
    if (h < 10) xr[h] = dx[n * 10 + h];
    __syncthreads();
    float acc = blin[h] + dis_emb[(size_t)dis_id[n] * HID + h];
#pragma unroll
    for (int k = 0; k < 10; ++k) acc += xr[k] * Wlin[k * HID + h];
    ushort_t hs = f2bf(acc);
    xh_dis[o] = hs;
    xl_dis[o] = f2bf(acc - bf2f(hs));
}

// ---------------- weight transpose + hi/lo split: W[K][N] f32 -> Wt_h/Wt_l [N][K] bf16
__global__ void k_trans(const float* __restrict__ W, ushort_t* __restrict__ th,
                        ushort_t* __restrict__ tl, int K, int N)
{
    __shared__ float sm[64][65];
    int n0 = blockIdx.x * 64, k0 = blockIdx.y * 64;
    int tx = threadIdx.x & 63, ty = threadIdx.x >> 6;
    for (int r = ty; r < 64; r += 4) sm[r][tx] = W[(size_t)(k0 + r) * N + n0 + tx];
    __syncthreads();
    for (int r = ty; r < 64; r += 4) {
        float v = sm[tx][r];
        ushort_t h = f2bf(v);
        float lo = v - bf2f(h);
        size_t o = (size_t)(n0 + r) * K + k0 + tx;
        th[o] = h;
        tl[o] = f2bf(lo);
    }
}

// ---------------- CSR build
__global__ void k_count(const int* __restrict__ dst, int n, int* __restrict__ cnt)
{
    int i = blockIdx.x * 256 + threadIdx.x;
    if (i < n) atomicAdd(&cnt[dst[i]], 1);
}

__global__ void k_scan(const int* __restrict__ cntA, int* __restrict__ offA,
                       const int* __restrict__ cntB, int* __restrict__ offB, int n)
{
    const int* cnt = blockIdx.x ? cntB : cntA;
    int* off = blockIdx.x ? offB : offA;
    __shared__ int sm[1024];
    __shared__ int carry;
    int tid = threadIdx.x;
    if (tid == 0) { carry = 0; off[0] = 0; }
    __syncthreads();
    for (int base = 0; base < n; base += 1024) {
        int i = base + tid;
        int v = (i < n) ? cnt[i] : 0;
        sm[tid] = v;
        __syncthreads();
        for (int o = 1; o < 1024; o <<= 1) {
            int t = (tid >= o) ? sm[tid - o] : 0;
            __syncthreads();
            sm[tid] += t;
            __syncthreads();
        }
        if (i < n) off[i + 1] = carry + sm[tid];
        int tot = sm[1023];
        __syncthreads();
        if (tid == 0) carry += tot;
        __syncthreads();
    }
}

__global__ void k_fill(const int* __restrict__ src, const int* __restrict__ dst, int n,
                       const int* __restrict__ off, int* __restrict__ cur, int* __restrict__ out)
{
    int i = blockIdx.x * 256 + threadIdx.x;
    if (i < n) {
        int d = dst[i];
        int p = atomicAdd(&cur[d], 1);
        out[off[d] + p] = src[i];
    }
}

// ---------------- mean aggregation from bf16-hi x; writes agg hi/lo bf16
__global__ void k_agg(const uint_t* __restrict__ x32, const int* __restrict__ off,
                      const int* __restrict__ csr, uint_t* __restrict__ aggh,
                      uint_t* __restrict__ aggl)
{
    int d = blockIdx.x;
    int t = threadIdx.x;       // 0..127
    int s = off[d], e = off[d + 1];
    float a0 = 0.f, a1 = 0.f;
    int i = s;
    for (; i + 4 <= e; i += 4) {
        int n0 = csr[i], n1 = csr[i + 1], n2 = csr[i + 2], n3 = csr[i + 3];
        uint_t v0 = x32[(size_t)n0 * 128 + t];
        uint_t v1 = x32[(size_t)n1 * 128 + t];
        uint_t v2 = x32[(size_t)n2 * 128 + t];
        uint_t v3 = x32[(size_t)n3 * 128 + t];
        a0 += bf2f(v0 & 0xffff) + bf2f(v1 & 0xffff) + bf2f(v2 & 0xffff) + bf2f(v3 & 0xffff);
        a1 += bf2f(v0 >> 16) + bf2f(v1 >> 16) + bf2f(v2 >> 16) + bf2f(v3 >> 16);
    }
    for (; i < e; ++i) {
        uint_t v = x32[(size_t)csr[i] * 128 + t];
        a0 += bf2f(v & 0xffff);
        a1 += bf2f(v >> 16);
    }
    float inv = 1.f / fmaxf((float)(e - s), 1.f);
    a0 *= inv; a1 *= inv;
    ushort_t h0 = f2bf(a0), h1 = f2bf(a1);
    aggh[(size_t)d * 128 + t] = (uint_t)h0 | ((uint_t)h1 << 16);
    ushort_t l0 = f2bf(a0 - bf2f(h0)), l1 = f2bf(a1 - bf2f(h1));
    aggl[(size_t)d * 128 + t] = (uint_t)l0 | ((uint_t)l1 << 16);
}

// ---------------- MFMA GEMM, bf16 hi/lo 3-product split precision
// BM=128, BN=128, BK=32, 4 waves (2x2), wave computes 64x64.
// 2-phase pipeline: STAGE(next buf) -> compute(cur) -> one __syncthreads.
// grid.x = mTiles*nTiles flattened, XCD-chunk swizzled; tile t: bm=t/nTiles, bn=t%nTiles.
template<int P, int G>
__global__ __launch_bounds__(256, 2) void k_mgemm(
    const ushort_t* __restrict__ A0h, const ushort_t* __restrict__ A0l,
    const ushort_t* __restrict__ A1h, const ushort_t* __restrict__ A1l,
    const int* __restrict__ ia, const int* __restrict__ ib, int row0,
    const ushort_t* __restrict__ W0h, const ushort_t* __restrict__ W0l,
    const ushort_t* __restrict__ W1h, const ushort_t* __restrict__ W1l,
    int wstride, int w1off,
    const float* __restrict__ bias, int M, int N, int Kp, int relu, int nTiles,
    ushort_t* __restrict__ Ch, ushort_t* __restrict__ Cl, float* __restrict__ Cf)
{
    __shared__ __align__(16) ushort_t lds[2][4][4096];  // [dbuf][Ah,Al,Bh,Bl][128x32]

    const int tid = threadIdx.x;
    const int lane = tid & 63;
    const int wv = tid >> 6;

    const int t = xcd_swz(blockIdx.x, gridDim.x);
    const int bm = (t / nTiles) * 128;
    const int bn = (t % nTiles) * 128;

    // staging: per plane 512 16B-chunks; thread covers chunks tid and tid+256.
    // chunk c -> row c>>2, k-offset (c&3)*8. LDS layout linear: chunk c at ushort 8c.
    const int rA0 = tid >> 2;
    const int rA1 = 64 + rA0;
    const int sk = (tid & 3) * 8;

    int tr0 = bm + rA0; if (tr0 > M - 1) tr0 = M - 1;
    int tr1 = bm + rA1; if (tr1 > M - 1) tr1 = M - 1;
    int r00, r01, r10, r11;
    if (G) {
        r00 = ia[row0 + tr0]; r01 = ia[row0 + tr1];
        r10 = ib[row0 + tr0]; r11 = ib[row0 + tr1];
    } else {
        r00 = tr0; r01 = tr1; r10 = tr0; r11 = tr1;
    }
    const size_t a0b0 = (size_t)r00 * Kp + sk;
    const size_t a1b0 = (size_t)r01 * Kp + sk;
    const size_t a0b1 = (size_t)r10 * Kp + sk;
    const size_t a1b1 = (size_t)r11 * Kp + sk;
    const size_t bb0 = (size_t)(bn + rA0) * wstride + sk;
    const size_t bb1 = (size_t)(bn + rA1) * wstride + sk;

    const int kpp = Kp >> 5;
    const int nsteps = P * kpp;

    auto STAGE = [&](int s, int b) {
        const int p = (P == 2 && s >= kpp) ? 1 : 0;
        const int k0 = (s - p * kpp) << 5;
        const ushort_t* Ah = p ? A1h : A0h;
        const ushort_t* Al = p ? A1l : A0l;
        const ushort_t* Wh = p ? W1h : W0h;
        const ushort_t* Wl = p ? W1l : W0l;
        const size_t a0 = (p ? a0b1 : a0b0) + k0;
        const size_t a1 = (p ? a1b1 : a1b0) + k0;
        const size_t wo = (size_t)(p ? w1off : 0) + k0;
        gl_lds16(Ah + a0, &lds[b][0][512 * wv]);
        gl_lds16(Ah + a1, &lds[b][0][2048 + 512 * wv]);
        gl_lds16(Al + a0, &lds[b][1][512 * wv]);
        gl_lds16(Al + a1, &lds[b][1][2048 + 512 * wv]);
        gl_lds16(Wh + bb0 + wo, &lds[b][2][512 * wv]);
        gl_lds16(Wh + bb1 + wo, &lds[b][2][2048 + 512 * wv]);
        gl_lds16(Wl + bb0 + wo, &lds[b][3][512 * wv]);
        gl_lds16(Wl + bb1 + wo, &lds[b][3][2048 + 512 * wv]);
    };

    f32x4 acc[4][4] = {};

    STAGE(0, 0);
    __syncthreads();

    const int arow = lane & 15;
    const int k8 = (lane >> 4) * 8;
    const int wrA = (wv >> 1) * 64;   // wave's A-row block within tile
    const int wrB = (wv & 1) * 64;    // wave's B-col block within tile

    for (int s = 0; s < nsteps; ++s) {
        const int cur = s & 1;
        if (s + 1 < nsteps) STAGE(s + 1, cur ^ 1);

        const ushort_t* Ahs = &lds[cur][0][0];
        const ushort_t* Als = &lds[cur][1][0];
        const ushort_t* Bhs = &lds[cur][2][0];
        const ushort_t* Bls = &lds[cur][3][0];

        s16x8 ah[4], al[4];
#pragma unroll
        for (int m = 0; m < 4; ++m) {
            const int ao = (wrA + m * 16 + arow) * 32 + k8;
            ah[m] = *(const s16x8*)&Ahs[ao];
            al[m] = *(const s16x8*)&Als[ao];
        }
#pragma unroll
        for (int n = 0; n < 4; ++n) {
            const int bo = (wrB + n * 16 + arow) * 32 + k8;
            s16x8 bh = *(const s16x8*)&Bhs[bo];
            s16x8 bl = *(const s16x8*)&Bls[bo];
#pragma unroll
            for (int m = 0; m < 4; ++m) {
                acc[m][n] = __builtin_amdgcn_mfma_f32_16x16x32_bf16(ah[m], bh, acc[m][n], 0, 0, 0);
                acc[m][n] = __builtin_amdgcn_mfma_f32_16x16x32_bf16(al[m], bh, acc[m][n], 0, 0, 0);
                acc[m][n] = __builtin_amdgcn_mfma_f32_16x16x32_bf16(ah[m], bl, acc[m][n], 0, 0, 0);
            }
        }
        __syncthreads();
    }

    // epilogue: C/D layout col=lane&15, row=(lane>>4)*4+j
    const int colC = lane & 15;
    const int rb = (lane >> 4) * 4;
#pragma unroll
    for (int m = 0; m < 4; ++m) {
#pragma unroll
        for (int j = 0; j < 4; ++j) {
            const int r = bm + wrA + m * 16 + rb + j;
            if (r < M) {
#pragma unroll
                for (int n = 0; n < 4; ++n) {
                    const int c = bn + wrB + n * 16 + colC;
                    if (c < N) {
                        float v = acc[m][n][j] + bias[c];
                        if (relu) v = fmaxf(v, 0.f);
                        if (Cf) {
                            Cf[(size_t)r * N + c] = v;
                        } else {
                            ushort_t h = f2bf(v);
                            Ch[(size_t)r * N + c] = h;
                            Cl[(size_t)r * N + c] = f2bf(v - bf2f(h));
                        }
                    }
                }
            }
        }
    }
}

// ---------------- fc4: out[r] = dot(e3[r,:64], w) + b
__global__ void k_fc4(const float* __restrict__ E3, const float* __restrict__ w,
                      const float* __restrict__ b, float* __restrict__ out, int M)
{
    int lane = threadIdx.x & 63;
    int row = blockIdx.x * 4 + (threadIdx.x >> 6);
    if (row >= M) return;
    float v = E3[(size_t)row * 64 + lane] * w[lane];
#pragma unroll
    for (int o = 32; o > 0; o >>= 1) v += __shfl_down(v, o);
    if (lane == 0) out[row] = v + b[0];
}

extern "C" void kernel_launch(void* const* d_in, const int* in_sizes, int n_in,
                              void* d_out, int out_size, void* d_ws, size_t ws_size,
                              hipStream_t stream)
{
    const int*   drug_id   = (const int*)d_in[0];
    const float* disease_x = (const float*)d_in[1];
    const int*   dis_id    = (const int*)d_in[2];
    const int*   e_mt      = (const int*)d_in[3];
    const int*   e_rev     = (const int*)d_in[4];
    const int*   e_lbl     = (const int*)d_in[5];
    const float* drug_emb  = (const float*)d_in[6];
    const float* dis_emb   = (const float*)d_in[7];
    const float* lin_w     = (const float*)d_in[8];
    const float* lin_b     = (const float*)d_in[9];
    const float* Wl_mt     = (const float*)d_in[10];
    const float* bl_mt     = (const float*)d_in[11];
    const float* Wr_mt     = (const float*)d_in[12];
    const float* Wl_rev    = (const float*)d_in[13];
    const float* bl_rev    = (const float*)d_in[14];
    const float* Wr_rev    = (const float*)d_in[15];
    const float* fc1_w = (const float*)d_in[16]; const float* fc1_b = (const float*)d_in[17];
    const float* fc2_w = (const float*)d_in[18]; const float* fc2_b = (const float*)d_in[19];
    const float* fc3_w = (const float*)d_in[20]; const float* fc3_b = (const float*)d_in[21];
    const float* fc4_w = (const float*)d_in[22]; const float* fc4_b = (const float*)d_in[23];
    float* out = (float*)d_out;

    // ---- workspace layout ----
    char* base = (char*)d_ws;
    size_t o = 0;
    auto alloc = [&](size_t bytes) { char* r = base + o; o += (bytes + 255) & ~(size_t)255; return r; };
    const size_t XB = (size_t)20000 * 256 * 2;   // one bf16 activation plane

    ushort_t* xh_dis  = (ushort_t*)alloc(XB);
    ushort_t* xl_dis  = (ushort_t*)alloc(XB);
    ushort_t* xh_drug = (ushort_t*)alloc(XB);
    ushort_t* xl_drug = (ushort_t*)alloc(XB);
    ushort_t* yh_dis  = (ushort_t*)alloc(XB);
    ushort_t* yl_dis  = (ushort_t*)alloc(XB);
    ushort_t* yh_drug = (ushort_t*)alloc(XB);
    ushort_t* yl_drug = (ushort_t*)alloc(XB);
    ushort_t* aggh    = (ushort_t*)alloc(XB);
    ushort_t* aggl    = (ushort_t*)alloc(XB);
    const size_t WB = (size_t)4 * 256 * 256 * 2; // 4-layer weight family, bf16
    ushort_t* wlmt_h  = (ushort_t*)alloc(WB); ushort_t* wlmt_l  = (ushort_t*)alloc(WB);
    ushort_t* wrmt_h  = (ushort_t*)alloc(WB); ushort_t* wrmt_l  = (ushort_t*)alloc(WB);
    ushort_t* wlrev_h = (ushort_t*)alloc(WB); ushort_t* wlrev_l = (ushort_t*)alloc(WB);
    ushort_t* wrrev_h = (ushort_t*)alloc(WB); ushort_t* wrrev_l = (ushort_t*)alloc(WB);
    ushort_t* fc1t_h  = (ushort_t*)alloc(512 * 256 * 2); ushort_t* fc1t_l = (ushort_t*)alloc(512 * 256 * 2);
    ushort_t* fc2t_h  = (ushort_t*)alloc(256 * 128 * 2); ushort_t* fc2t_l = (ushort_t*)alloc(256 * 128 * 2);
    // fc3 weight padded to 128 N-rows (BN=128 kernel); upper 64 rows zero
    ushort_t* fc3t_h  = (ushort_t*)alloc(128 * 128 * 2); ushort_t* fc3t_l = (ushort_t*)alloc(128 * 128 * 2);
    // CSR counters/cursors: ONE contiguous block so a single memset covers it
    int* cnts     = (int*)alloc(80000 * 4);
    int* cnt_dis  = cnts;
    int* cnt_drug = cnts + 20000;
    int* cur_dis  = cnts + 40000;
    int* cur_drug = cnts + 60000;
    int* off_dis  = (int*)alloc(20004 * 4);
    int* off_drug = (int*)alloc(20004 * 4);
    int* csr_mt   = (int*)alloc(400000 * 4);
    int* csr_rev  = (int*)alloc(400000 * 4);
    // classifier aliases (dead buffers at that point)
    ushort_t* e1h = aggh;            ushort_t* e1l = aggl;            // [20000][256]
    ushort_t* e2h = yh_dis;          ushort_t* e2l = yl_dis;          // [20000][128]
    float*    e3  = (float*)yh_drug;                                  // [20000][64] f32

    hipMemsetAsync(cnts, 0, 80000 * sizeof(int), stream);
    hipMemsetAsync(fc3t_h, 0, 128 * 128 * 2, stream);
    hipMemsetAsync(fc3t_l, 0, 128 * 128 * 2, stream);

    // weight prep: transpose + hi/lo split
    const float* wfam[4] = { Wl_mt, Wr_mt, Wl_rev, Wr_rev };
    ushort_t* wth[4] = { wlmt_h, wrmt_h, wlrev_h, wrrev_h };
    ushort_t* wtl[4] = { wlmt_l, wrmt_l, wlrev_l, wrrev_l };
    for (int f = 0; f < 4; ++f)
        for (int l = 0; l < NLAYERS; ++l)
            k_trans<<<dim3(4, 4), 256, 0, stream>>>(wfam[f] + (size_t)l * 65536,
                                                    wth[f] + (size_t)l * 65536,
                                                    wtl[f] + (size_t)l * 65536, 256, 256);
    k_trans<<<dim3(4, 8), 256, 0, stream>>>(fc1_w, fc1t_h, fc1t_l, 512, 256);
    k_trans<<<dim3(2, 4), 256, 0, stream>>>(fc2_w, fc2t_h, fc2t_l, 256, 128);
    k_trans<<<dim3(1, 2), 256, 0, stream>>>(fc3_w, fc3t_h, fc3t_l, 128, 64);

    k_init<<<NDRUG, HID, 0, stream>>>(drug_id, drug_emb, disease_x, lin_w, lin_b,
                                      dis_id, dis_emb, xh_drug, xl_drug, xh_dis, xl_dis);
    int nbE = (NE + 255) / 256;
    k_count<<<nbE, 256, 0, stream>>>(e_mt + NE, NE, cnt_dis);
    k_count<<<nbE, 256, 0, stream>>>(e_rev + NE, NE, cnt_drug);
    k_scan<<<2, 1024, 0, stream>>>(cnt_dis, off_dis, cnt_drug, off_drug, 20000);
    k_fill<<<nbE, 256, 0, stream>>>(e_mt, e_mt + NE, NE, off_dis, cur_dis, csr_mt);
    k_fill<<<nbE, 256, 0, stream>>>(e_rev, e_rev + NE, NE, off_drug, cur_drug, csr_rev);

    ushort_t *xdh = xh_dis, *xdl = xl_dis, *xgh = xh_drug, *xgl = xl_drug;
    ushort_t *tdh = yh_dis, *tdl = yl_dis, *tgh = yh_drug, *tgl = yl_drug;
    const int mT = 157;                     // ceil(20000/128)
    for (int l = 0; l < NLAYERS; ++l) {
        int relu = (l < NLAYERS - 1) ? 1 : 0;
        size_t wo = (size_t)l * 65536;
        // disease side: agg over may_treat (drug->disease), then h_dis
        k_agg<<<NDIS, 128, 0, stream>>>((const uint_t*)xgh, off_dis, csr_mt,
                                        (uint_t*)aggh, (uint_t*)aggl);
        k_mgemm<2, 0><<<mT * 2, 256, 0, stream>>>(
            aggh, aggl, xdh, xdl, nullptr, nullptr, 0,
            wlmt_h + wo, wlmt_l + wo, wrmt_h + wo, wrmt_l + wo, 256, 0,
            bl_mt + l * HID, NDIS, 256, 256, relu, 2, tdh, tdl, nullptr);
        // drug side: agg over rev (disease->drug), then h_drug (xdh still intact)
        k_agg<<<NDRUG, 128, 0, stream>>>((const uint_t*)xdh, off_drug, csr_rev,
                                         (uint_t*)aggh, (uint_t*)aggl);
        k_mgemm<2, 0><<<mT * 2, 256, 0, stream>>>(
            aggh, aggl, xgh, xgl, nullptr, nullptr, 0,
            wlrev_h + wo, wlrev_l + wo, wrrev_h + wo, wrrev_l + wo, 256, 0,
            bl_rev + l * HID, NDRUG, 256, 256, relu, 2, tgh, tgl, nullptr);
        ushort_t* t;
        t = xdh; xdh = tdh; tdh = t;  t = xdl; xdl = tdl; tdl = t;
        t = xgh; xgh = tgh; tgh = t;  t = xgl; xgl = tgl; tgl = t;
    }

    // classifier, 5 chunks of 20000 label edges
    for (int c = 0; c < NEL; c += 20000) {
        int Mc = 20000;
        k_mgemm<2, 1><<<mT * 2, 256, 0, stream>>>(
            xgh, xgl, xdh, xdl, e_lbl, e_lbl + NEL, c,
            fc1t_h, fc1t_l, fc1t_h, fc1t_l, 512, 256,
            fc1_b, Mc, 256, 256, 1, 2, e1h, e1l, nullptr);
        k_mgemm<1, 0><<<mT, 256, 0, stream>>>(
            e1h, e1l, nullptr, nullptr, nullptr, nullptr, 0,
            fc2t_h, fc2t_l, nullptr, nullptr, 256, 0,
            fc2_b, Mc, 128, 256, 1, 1, e2h, e2l, nullptr);
        k_mgemm<1, 0><<<mT, 256, 0, stream>>>(
            e2h, e2l, nullptr, nullptr, nullptr, nullptr, 0,
            fc3t_h, fc3t_l, nullptr, nullptr, 128, 0,
            fc3_b, Mc, 64, 128, 1, 1, nullptr, nullptr, e3);
        k_fc4<<<(Mc + 3) / 4, 256, 0, stream>>>(e3, fc4_w, fc4_b, out + c, Mc);
    }
}

// Round 5
// 986.654 us; speedup vs baseline: 1.1747x; 1.1747x over previous
//
#include <hip/hip_runtime.h>

#define HID 256
#define NDRUG 20000
#define NDIS 20000
#define NE 400000
#define NEL 100000
#define NLAYERS 4

typedef float f32x4 __attribute__((ext_vector_type(4)));
typedef short s16x8 __attribute__((ext_vector_type(8)));
typedef unsigned short ushort_t;
typedef unsigned int uint_t;

// ---- bf16 helpers (round-to-nearest-even) ----
__device__ __forceinline__ ushort_t f2bf(float f) {
    uint_t u = __float_as_uint(f);
    u += 0x7fffu + ((u >> 16) & 1u);
    return (ushort_t)(u >> 16);
}
__device__ __forceinline__ float bf2f(ushort_t h) {
    return __uint_as_float(((uint_t)h) << 16);
}

// ---- async global->LDS, 16B per lane; lptr must be wave-uniform base ----
__device__ __forceinline__ void gl_lds16(const void* g, void* l) {
    __builtin_amdgcn_global_load_lds(
        (const __attribute__((address_space(1))) void*)g,
        (__attribute__((address_space(3))) void*)l, 16, 0, 0);
}

// ---- m204 bijective XCD-chunked swizzle ----
__device__ __forceinline__ int xcd_swz(int orig, int nwg) {
    int q = nwg >> 3, r = nwg & 7;
    int x = orig & 7, i = orig >> 3;
    int start = (x < r) ? x * (q + 1) : r * (q + 1) + (x - r) * q;
    return start + i;
}

// ---------------- init
__global__ void k_init(const int* __restrict__ drug_id, const float* __restrict__ drug_emb,
                       const float* __restrict__ dx, const float* __restrict__ Wlin,
                       const float* __restrict__ blin, const int* __restrict__ dis_id,
                       const float* __restrict__ dis_emb,
                       ushort_t* __restrict__ xh_drug, ushort_t* __restrict__ xl_drug,
                       ushort_t* __restrict__ xh_dis, ushort_t* __restrict__ xl_dis)
{
    int n = blockIdx.x; int h = threadIdx.x;
    size_t o = (size_t)n * HID + h;
    float vd = drug_emb[(size_t)drug_id[n] * HID + h];
    ushort_t hd = f2bf(vd);
    xh_drug[o] = hd;
    xl_drug[o] = f2bf(vd - bf2f(hd));

    __shared__ float xr[10];
    if (h < 10) xr[h] = dx[n * 10 + h];
    __syncthreads();
    float acc = blin[h] + dis_emb[(size_t)dis_id[n] * HID + h];
#pragma unroll
    for (int k = 0; k < 10; ++k) acc += xr[k] * Wlin[k * HID + h];
    ushort_t hs = f2bf(acc);
    xh_dis[o] = hs;
    xl_dis[o] = f2bf(acc - bf2f(hs));
}

// ---------------- weight transpose + hi/lo split: W[K][N] f32 -> Wt[N][K] bf16
__global__ void k_trans(const float* __restrict__ W, ushort_t* __restrict__ th,
                        ushort_t* __restrict__ tl, int K, int N)
{
    __shared__ float sm[64][65];
    int n0 = blockIdx.x * 64, k0 = blockIdx.y * 64;
    int tx = threadIdx.x & 63, ty = threadIdx.x >> 6;
    for (int r = ty; r < 64; r += 4) sm[r][tx] = W[(size_t)(k0 + r) * N + n0 + tx];
    __syncthreads();
    for (int r = ty; r < 64; r += 4) {
        float v = sm[tx][r];
        ushort_t h = f2bf(v);
        float lo = v - bf2f(h);
        size_t o = (size_t)(n0 + r) * K + k0 + tx;
        th[o] = h;
        tl[o] = f2bf(lo);
    }
}

// ---------------- CSR build
__global__ void k_count(const int* __restrict__ dst, int n, int* __restrict__ cnt)
{
    int i = blockIdx.x * 256 + threadIdx.x;
    if (i < n) atomicAdd(&cnt[dst[i]], 1);
}

__global__ void k_scan(const int* __restrict__ cntA, int* __restrict__ offA,
                       const int* __restrict__ cntB, int* __restrict__ offB, int n)
{
    const int* cnt = blockIdx.x ? cntB : cntA;
    int* off = blockIdx.x ? offB : offA;
    __shared__ int sm[1024];
    __shared__ int carry;
    int tid = threadIdx.x;
    if (tid == 0) { carry = 0; off[0] = 0; }
    __syncthreads();
    for (int base = 0; base < n; base += 1024) {
        int i = base + tid;
        int v = (i < n) ? cnt[i] : 0;
        sm[tid] = v;
        __syncthreads();
        for (int o = 1; o < 1024; o <<= 1) {
            int t = (tid >= o) ? sm[tid - o] : 0;
            __syncthreads();
            sm[tid] += t;
            __syncthreads();
        }
        if (i < n) off[i + 1] = carry + sm[tid];
        int tot = sm[1023];
        __syncthreads();
        if (tid == 0) carry += tot;
        __syncthreads();
    }
}

__global__ void k_fill(const int* __restrict__ src, const int* __restrict__ dst, int n,
                       const int* __restrict__ off, int* __restrict__ cur, int* __restrict__ out)
{
    int i = blockIdx.x * 256 + threadIdx.x;
    if (i < n) {
        int d = dst[i];
        int p = atomicAdd(&cur[d], 1);
        out[off[d] + p] = src[i];
    }
}

// ---------------- fused dual mean-aggregation (hi-only output)
// blocks [0,NDIS) = side0, [NDIS,NDIS+NDRUG) = side1; 128 thr, 2 h-dims each
__global__ void k_agg2(const uint_t* __restrict__ x0, const int* __restrict__ off0,
                       const int* __restrict__ csr0, uint_t* __restrict__ o0,
                       const uint_t* __restrict__ x1, const int* __restrict__ off1,
                       const int* __restrict__ csr1, uint_t* __restrict__ o1)
{
    int d = blockIdx.x;
    const uint_t* x; const int* off; const int* csr; uint_t* ou;
    if (d < NDIS) { x = x0; off = off0; csr = csr0; ou = o0; }
    else { d -= NDIS; x = x1; off = off1; csr = csr1; ou = o1; }
    int t = threadIdx.x;
    int s = off[d], e = off[d + 1];
    float a0 = 0.f, a1 = 0.f;
    int i = s;
    for (; i + 4 <= e; i += 4) {
        int n0 = csr[i], n1 = csr[i + 1], n2 = csr[i + 2], n3 = csr[i + 3];
        uint_t v0 = x[(size_t)n0 * 128 + t];
        uint_t v1 = x[(size_t)n1 * 128 + t];
        uint_t v2 = x[(size_t)n2 * 128 + t];
        uint_t v3 = x[(size_t)n3 * 128 + t];
        a0 += bf2f(v0 & 0xffff) + bf2f(v1 & 0xffff) + bf2f(v2 & 0xffff) + bf2f(v3 & 0xffff);
        a1 += bf2f(v0 >> 16) + bf2f(v1 >> 16) + bf2f(v2 >> 16) + bf2f(v3 >> 16);
    }
    for (; i < e; ++i) {
        uint_t v = x[(size_t)csr[i] * 128 + t];
        a0 += bf2f(v & 0xffff);
        a1 += bf2f(v >> 16);
    }
    float inv = 1.f / fmaxf((float)(e - s), 1.f);
    a0 *= inv; a1 *= inv;
    ou[(size_t)d * 128 + t] = (uint_t)f2bf(a0) | ((uint_t)f2bf(a1) << 16);
}

// ---------------- MFMA GEMM job descriptor
struct GJob {
    const ushort_t *A0h, *A0l, *A1h, *A1l;
    const int *ia, *ib;
    int row0;
    const ushort_t *W0h, *W0l, *W1h, *W1l;
    int wstride, w1off;
    const float* bias;
    int M, N, Kp, relu, nTiles;
    ushort_t *Ch, *Cl;
    float* Cf;
};

// BM=BN=128, BK=32, 4 waves (2x2). Counted-vmcnt 2-phase pipeline:
// STAGE(s+1) -> s_waitcnt vmcnt(#issued) -> s_barrier -> compute(cur) -> s_barrier.
// AL0: pass0 has an A-lo plane (3 products) or not (2 products).
template<int P, int G, int AL0>
__global__ __launch_bounds__(256, 2) void k_mgemm(GJob j0, GJob j1, int blocks0)
{
    __shared__ __align__(16) ushort_t lds[2][4][4096];  // [dbuf][Ah,Al,Bh,Bl][128x32]

    const int tid = threadIdx.x;
    const int lane = tid & 63;
    const int wv = tid >> 6;

    const int bid = blockIdx.x;
    const bool second = (bid >= blocks0);
    const GJob j = second ? j1 : j0;
    const int nblk = second ? ((int)gridDim.x - blocks0) : blocks0;
    const int tloc = second ? (bid - blocks0) : bid;
    const int t = xcd_swz(tloc, nblk);
    const int bm = ((j.nTiles == 2) ? (t >> 1) : t) * 128;
    const int bn = ((j.nTiles == 2) ? (t & 1) : 0) * 128;

    // staging geometry: chunk tid -> row tid>>2, k-offset (tid&3)*8 ushorts
    const int rA0 = tid >> 2;
    const int sk = (tid & 3) * 8;

    int tr0 = bm + rA0;      if (tr0 > j.M - 1) tr0 = j.M - 1;
    int tr1 = bm + 64 + rA0; if (tr1 > j.M - 1) tr1 = j.M - 1;
    int r00, r01, r10, r11;
    if (G) {
        r00 = j.ia[j.row0 + tr0]; r01 = j.ia[j.row0 + tr1];
        r10 = j.ib[j.row0 + tr0]; r11 = j.ib[j.row0 + tr1];
    } else {
        r00 = tr0; r01 = tr1; r10 = tr0; r11 = tr1;
    }
    const size_t a0b0 = (size_t)r00 * j.Kp + sk;
    const size_t a1b0 = (size_t)r01 * j.Kp + sk;
    const size_t a0b1 = (size_t)r10 * j.Kp + sk;
    const size_t a1b1 = (size_t)r11 * j.Kp + sk;
    const size_t bb0 = (size_t)(bn + rA0) * j.wstride + sk;
    const size_t bb1 = (size_t)(bn + 64 + rA0) * j.wstride + sk;

    const int kpp = j.Kp >> 5;
    const int nsteps = P * kpp;

    auto STAGE = [&](int s, int b) {
        const int p = (P == 2 && s >= kpp) ? 1 : 0;
        const int k0 = (s - p * kpp) << 5;
        const ushort_t* Ah = p ? j.A1h : j.A0h;
        const ushort_t* Al = p ? j.A1l : j.A0l;
        const ushort_t* Wh = p ? j.W1h : j.W0h;
        const ushort_t* Wl = p ? j.W1l : j.W0l;
        const size_t a0 = (p ? a0b1 : a0b0) + k0;
        const size_t a1 = (p ? a1b1 : a1b0) + k0;
        const size_t wo = (size_t)(p ? j.w1off : 0) + k0;
        gl_lds16(Ah + a0, &lds[b][0][512 * wv]);
        gl_lds16(Ah + a1, &lds[b][0][2048 + 512 * wv]);
        if (AL0 || p) {
            gl_lds16(Al + a0, &lds[b][1][512 * wv]);
            gl_lds16(Al + a1, &lds[b][1][2048 + 512 * wv]);
        }
        gl_lds16(Wh + bb0 + wo, &lds[b][2][512 * wv]);
        gl_lds16(Wh + bb1 + wo, &lds[b][2][2048 + 512 * wv]);
        gl_lds16(Wl + bb0 + wo, &lds[b][3][512 * wv]);
        gl_lds16(Wl + bb1 + wo, &lds[b][3][2048 + 512 * wv]);
    };

    f32x4 acc[4][4] = {};

    const int arow = lane & 15;
    const int k8 = (lane >> 4) * 8;
    const int wrA = (wv >> 1) * 64;
    const int wrB = (wv & 1) * 64;

    STAGE(0, 0);

    for (int s = 0; s < nsteps; ++s) {
        const int cur = s & 1;
        const bool last = (s + 1 == nsteps);
        if (!last) STAGE(s + 1, cur ^ 1);
        // wait only for the PREVIOUS step's loads; just-issued stay in flight
        if (last) {
            asm volatile("s_waitcnt vmcnt(0)" ::: "memory");
        } else if (AL0 || (P == 2 && s + 1 >= kpp)) {
            asm volatile("s_waitcnt vmcnt(8)" ::: "memory");
        } else {
            asm volatile("s_waitcnt vmcnt(6)" ::: "memory");
        }
        __builtin_amdgcn_sched_barrier(0);
        __builtin_amdgcn_s_barrier();

        const bool hasAL = AL0 || (P == 2 && s >= kpp);
        const ushort_t* Ahs = &lds[cur][0][0];
        const ushort_t* Als = &lds[cur][1][0];
        const ushort_t* Bhs = &lds[cur][2][0];
        const ushort_t* Bls = &lds[cur][3][0];

        s16x8 ah[4], al[4];
#pragma unroll
        for (int m = 0; m < 4; ++m) {
            const int ao = (wrA + m * 16 + arow) * 32 + k8;
            ah[m] = *(const s16x8*)&Ahs[ao];
            if (hasAL) al[m] = *(const s16x8*)&Als[ao];
        }
#pragma unroll
        for (int n = 0; n < 4; ++n) {
            const int bo = (wrB + n * 16 + arow) * 32 + k8;
            s16x8 bh = *(const s16x8*)&Bhs[bo];
            s16x8 bl = *(const s16x8*)&Bls[bo];
#pragma unroll
            for (int m = 0; m < 4; ++m) {
                acc[m][n] = __builtin_amdgcn_mfma_f32_16x16x32_bf16(ah[m], bh, acc[m][n], 0, 0, 0);
                acc[m][n] = __builtin_amdgcn_mfma_f32_16x16x32_bf16(ah[m], bl, acc[m][n], 0, 0, 0);
            }
        }
        if (hasAL) {
#pragma unroll
            for (int n = 0; n < 4; ++n) {
                const int bo = (wrB + n * 16 + arow) * 32 + k8;
                s16x8 bh = *(const s16x8*)&Bhs[bo];
#pragma unroll
                for (int m = 0; m < 4; ++m)
                    acc[m][n] = __builtin_amdgcn_mfma_f32_16x16x32_bf16(al[m], bh, acc[m][n], 0, 0, 0);
            }
        }
        __builtin_amdgcn_s_barrier();
    }

    // epilogue: C/D layout col=lane&15, row=(lane>>4)*4+j
    const int colC = lane & 15;
    const int rb = (lane >> 4) * 4;
#pragma unroll
    for (int m = 0; m < 4; ++m) {
#pragma unroll
        for (int jj = 0; jj < 4; ++jj) {
            const int r = bm + wrA + m * 16 + rb + jj;
            if (r < j.M) {
#pragma unroll
                for (int n = 0; n < 4; ++n) {
                    const int c = bn + wrB + n * 16 + colC;
                    if (c < j.N) {
                        float v = acc[m][n][jj] + j.bias[c];
                        if (j.relu) v = fmaxf(v, 0.f);
                        if (j.Cf) {
                            j.Cf[(size_t)r * j.N + c] = v;
                        } else {
                            ushort_t h = f2bf(v);
                            j.Ch[(size_t)r * j.N + c] = h;
                            j.Cl[(size_t)r * j.N + c] = f2bf(v - bf2f(h));
                        }
                    }
                }
            }
        }
    }
}

// ---------------- fc4
__global__ void k_fc4(const float* __restrict__ E3, const float* __restrict__ w,
                      const float* __restrict__ b, float* __restrict__ out, int M)
{
    int lane = threadIdx.x & 63;
    int row = blockIdx.x * 4 + (threadIdx.x >> 6);
    if (row >= M) return;
    float v = E3[(size_t)row * 64 + lane] * w[lane];
#pragma unroll
    for (int o = 32; o > 0; o >>= 1) v += __shfl_down(v, o);
    if (lane == 0) out[row] = v + b[0];
}

extern "C" void kernel_launch(void* const* d_in, const int* in_sizes, int n_in,
                              void* d_out, int out_size, void* d_ws, size_t ws_size,
                              hipStream_t stream)
{
    const int*   drug_id   = (const int*)d_in[0];
    const float* disease_x = (const float*)d_in[1];
    const int*   dis_id    = (const int*)d_in[2];
    const int*   e_mt      = (const int*)d_in[3];
    const int*   e_rev     = (const int*)d_in[4];
    const int*   e_lbl     = (const int*)d_in[5];
    const float* drug_emb  = (const float*)d_in[6];
    const float* dis_emb   = (const float*)d_in[7];
    const float* lin_w     = (const float*)d_in[8];
    const float* lin_b     = (const float*)d_in[9];
    const float* Wl_mt     = (const float*)d_in[10];
    const float* bl_mt     = (const float*)d_in[11];
    const float* Wr_mt     = (const float*)d_in[12];
    const float* Wl_rev    = (const float*)d_in[13];
    const float* bl_rev    = (const float*)d_in[14];
    const float* Wr_rev    = (const float*)d_in[15];
    const float* fc1_w = (const float*)d_in[16]; const float* fc1_b = (const float*)d_in[17];
    const float* fc2_w = (const float*)d_in[18]; const float* fc2_b = (const float*)d_in[19];
    const float* fc3_w = (const float*)d_in[20]; const float* fc3_b = (const float*)d_in[21];
    const float* fc4_w = (const float*)d_in[22]; const float* fc4_b = (const float*)d_in[23];
    float* out = (float*)d_out;

    // ---- workspace layout (same footprint as round 4) ----
    char* base = (char*)d_ws;
    size_t o = 0;
    auto alloc = [&](size_t bytes) { char* r = base + o; o += (bytes + 255) & ~(size_t)255; return r; };
    const size_t XB = (size_t)20000 * 256 * 2;   // one bf16 activation plane (10.24MB)

    ushort_t* xh_dis  = (ushort_t*)alloc(XB);
    ushort_t* xl_dis  = (ushort_t*)alloc(XB);
    ushort_t* xh_drug = (ushort_t*)alloc(XB);
    ushort_t* xl_drug = (ushort_t*)alloc(XB);
    ushort_t* yh_dis  = (ushort_t*)alloc(XB);    // y planes: 4 contiguous
    ushort_t* yl_dis  = (ushort_t*)alloc(XB);
    ushort_t* yh_drug = (ushort_t*)alloc(XB);
    ushort_t* yl_drug = (ushort_t*)alloc(XB);
    ushort_t* agg_dis = (ushort_t*)alloc(XB);    // hi-only agg, both sides
    ushort_t* agg_drug= (ushort_t*)alloc(XB);
    const size_t WB = (size_t)4 * 256 * 256 * 2;
    ushort_t* wlmt_h  = (ushort_t*)alloc(WB); ushort_t* wlmt_l  = (ushort_t*)alloc(WB);
    ushort_t* wrmt_h  = (ushort_t*)alloc(WB); ushort_t* wrmt_l  = (ushort_t*)alloc(WB);
    ushort_t* wlrev_h = (ushort_t*)alloc(WB); ushort_t* wlrev_l = (ushort_t*)alloc(WB);
    ushort_t* wrrev_h = (ushort_t*)alloc(WB); ushort_t* wrrev_l = (ushort_t*)alloc(WB);
    ushort_t* fc1t_h  = (ushort_t*)alloc(512 * 256 * 2); ushort_t* fc1t_l = (ushort_t*)alloc(512 * 256 * 2);
    ushort_t* fc2t_h  = (ushort_t*)alloc(256 * 128 * 2); ushort_t* fc2t_l = (ushort_t*)alloc(256 * 128 * 2);
    ushort_t* fc3t_h  = (ushort_t*)alloc(128 * 128 * 2); ushort_t* fc3t_l = (ushort_t*)alloc(128 * 128 * 2);
    int* cnts     = (int*)alloc(80000 * 4);
    int* cnt_dis  = cnts;
    int* cnt_drug = cnts + 20000;
    int* cur_dis  = cnts + 40000;
    int* cur_drug = cnts + 60000;
    int* off_dis  = (int*)alloc(20004 * 4);
    int* off_drug = (int*)alloc(20004 * 4);
    int* csr_mt   = (int*)alloc(400000 * 4);
    int* csr_rev  = (int*)alloc(400000 * 4);
    // classifier aliases (chunk = 40000 rows):
    // e1 hi = [yh_dis..yl_dis], e1 lo = [yh_drug..yl_drug]  (40000x256 each)
    // e2 hi = agg_dis, e2 lo = agg_drug                     (40000x128 each)
    // e3 f32 = yh_dis region (e1 dead during fc3)           (40000x64)
    ushort_t* e1h = yh_dis;
    ushort_t* e1l = yh_drug;
    ushort_t* e2h = agg_dis;
    ushort_t* e2l = agg_drug;
    float*    e3  = (float*)yh_dis;

    hipMemsetAsync(cnts, 0, 80000 * sizeof(int), stream);
    hipMemsetAsync(fc3t_h, 0, 128 * 128 * 2, stream);
    hipMemsetAsync(fc3t_l, 0, 128 * 128 * 2, stream);

    const float* wfam[4] = { Wl_mt, Wr_mt, Wl_rev, Wr_rev };
    ushort_t* wth[4] = { wlmt_h, wrmt_h, wlrev_h, wrrev_h };
    ushort_t* wtl[4] = { wlmt_l, wrmt_l, wlrev_l, wrrev_l };
    for (int f = 0; f < 4; ++f)
        for (int l = 0; l < NLAYERS; ++l)
            k_trans<<<dim3(4, 4), 256, 0, stream>>>(wfam[f] + (size_t)l * 65536,
                                                    wth[f] + (size_t)l * 65536,
                                                    wtl[f] + (size_t)l * 65536, 256, 256);
    k_trans<<<dim3(4, 8), 256, 0, stream>>>(fc1_w, fc1t_h, fc1t_l, 512, 256);
    k_trans<<<dim3(2, 4), 256, 0, stream>>>(fc2_w, fc2t_h, fc2t_l, 256, 128);
    k_trans<<<dim3(1, 2), 256, 0, stream>>>(fc3_w, fc3t_h, fc3t_l, 128, 64);

    k_init<<<NDRUG, HID, 0, stream>>>(drug_id, drug_emb, disease_x, lin_w, lin_b,
                                      dis_id, dis_emb, xh_drug, xl_drug, xh_dis, xl_dis);
    int nbE = (NE + 255) / 256;
    k_count<<<nbE, 256, 0, stream>>>(e_mt + NE, NE, cnt_dis);
    k_count<<<nbE, 256, 0, stream>>>(e_rev + NE, NE, cnt_drug);
    k_scan<<<2, 1024, 0, stream>>>(cnt_dis, off_dis, cnt_drug, off_drug, 20000);
    k_fill<<<nbE, 256, 0, stream>>>(e_mt, e_mt + NE, NE, off_dis, cur_dis, csr_mt);
    k_fill<<<nbE, 256, 0, stream>>>(e_rev, e_rev + NE, NE, off_drug, cur_drug, csr_rev);

    ushort_t *xdh = xh_dis, *xdl = xl_dis, *xgh = xh_drug, *xgl = xl_drug;
    ushort_t *tdh = yh_dis, *tdl = yl_dis, *tgh = yh_drug, *tgl = yl_drug;
    const int mT = 157;                     // ceil(20000/128)
    for (int l = 0; l < NLAYERS; ++l) {
        int relu = (l < NLAYERS - 1) ? 1 : 0;
        size_t wo = (size_t)l * 65536;
        // fused aggregations: agg_dis <- mean(xgh over mt), agg_drug <- mean(xdh over rev)
        k_agg2<<<NDIS + NDRUG, 128, 0, stream>>>(
            (const uint_t*)xgh, off_dis, csr_mt, (uint_t*)agg_dis,
            (const uint_t*)xdh, off_drug, csr_rev, (uint_t*)agg_drug);
        // fused dual-side GEMM
        GJob jd = { agg_dis, nullptr, xdh, xdl, nullptr, nullptr, 0,
                    wlmt_h + wo, wlmt_l + wo, wrmt_h + wo, wrmt_l + wo, 256, 0,
                    bl_mt + l * HID, NDIS, 256, 256, relu, 2, tdh, tdl, nullptr };
        GJob jg = { agg_drug, nullptr, xgh, xgl, nullptr, nullptr, 0,
                    wlrev_h + wo, wlrev_l + wo, wrrev_h + wo, wrrev_l + wo, 256, 0,
                    bl_rev + l * HID, NDRUG, 256, 256, relu, 2, tgh, tgl, nullptr };
        k_mgemm<2, 0, 0><<<mT * 4, 256, 0, stream>>>(jd, jg, mT * 2);
        ushort_t* t;
        t = xdh; xdh = tdh; tdh = t;  t = xdl; xdl = tdl; tdl = t;
        t = xgh; xgh = tgh; tgh = t;  t = xgl; xgl = tgl; tgl = t;
    }
    // after 4 swaps x* point at the original x planes; y/agg planes are dead

    // classifier: 3 chunks of up to 40000 label edges
    for (int c = 0; c < NEL; c += 40000) {
        int Mc = (NEL - c < 40000) ? (NEL - c) : 40000;
        int mT1 = (Mc + 127) / 128;
        GJob f1 = { xgh, xgl, xdh, xdl, e_lbl, e_lbl + NEL, c,
                    fc1t_h, fc1t_l, fc1t_h, fc1t_l, 512, 256,
                    fc1_b, Mc, 256, 256, 1, 2, e1h, e1l, nullptr };
        k_mgemm<2, 1, 1><<<mT1 * 2, 256, 0, stream>>>(f1, f1, mT1 * 2);
        GJob f2 = { e1h, e1l, nullptr, nullptr, nullptr, nullptr, 0,
                    fc2t_h, fc2t_l, nullptr, nullptr, 256, 0,
                    fc2_b, Mc, 128, 256, 1, 1, e2h, e2l, nullptr };
        k_mgemm<1, 0, 1><<<mT1, 256, 0, stream>>>(f2, f2, mT1);
        GJob f3 = { e2h, e2l, nullptr, nullptr, nullptr, nullptr, 0,
                    fc3t_h, fc3t_l, nullptr, nullptr, 128, 0,
                    fc3_b, Mc, 64, 128, 1, 1, nullptr, nullptr, e3 };
        k_mgemm<1, 0, 1><<<mT1, 256, 0, stream>>>(f3, f3, mT1);
        k_fc4<<<(Mc + 3) / 4, 256, 0, stream>>>(e3, fc4_w, fc4_b, out + c, Mc);
    }
}

// Round 6
// 919.912 us; speedup vs baseline: 1.2599x; 1.0726x over previous
//
#include <hip/hip_runtime.h>

#define HID 256
#define NDRUG 20000
#define NDIS 20000
#define NE 400000
#define NEL 100000
#define NLAYERS 4

typedef float f32x4 __attribute__((ext_vector_type(4)));
typedef short s16x8 __attribute__((ext_vector_type(8)));
typedef unsigned short ushort_t;
typedef unsigned int uint_t;

// ---- bf16 helpers (round-to-nearest-even) ----
__device__ __forceinline__ ushort_t f2bf(float f) {
    uint_t u = __float_as_uint(f);
    u += 0x7fffu + ((u >> 16) & 1u);
    return (ushort_t)(u >> 16);
}
__device__ __forceinline__ float bf2f(ushort_t h) {
    return __uint_as_float(((uint_t)h) << 16);
}

// ---- async global->LDS, 16B per lane; LDS base must be wave-uniform ----
__device__ __forceinline__ void gl_lds16(const void* g, void* l) {
    __builtin_amdgcn_global_load_lds(
        (const __attribute__((address_space(1))) void*)g,
        (__attribute__((address_space(3))) void*)l, 16, 0, 0);
}

// ---- m204 bijective XCD-chunked swizzle ----
__device__ __forceinline__ int xcd_swz(int orig, int nwg) {
    int q = nwg >> 3, r = nwg & 7;
    int x = orig & 7, i = orig >> 3;
    int start = (x < r) ? x * (q + 1) : r * (q + 1) + (x - r) * q;
    return start + i;
}

// ---------------- init
__global__ void k_init(const int* __restrict__ drug_id, const float* __restrict__ drug_emb,
                       const float* __restrict__ dx, const float* __restrict__ Wlin,
                       const float* __restrict__ blin, const int* __restrict__ dis_id,
                       const float* __restrict__ dis_emb,
                       ushort_t* __restrict__ xh_drug, ushort_t* __restrict__ xl_drug,
                       ushort_t* __restrict__ xh_dis, ushort_t* __restrict__ xl_dis)
{
    int n = blockIdx.x; int h = threadIdx.x;
    size_t o = (size_t)n * HID + h;
    float vd = drug_emb[(size_t)drug_id[n] * HID + h];
    ushort_t hd = f2bf(vd);
    xh_drug[o] = hd;
    xl_drug[o] = f2bf(vd - bf2f(hd));

    __shared__ float xr[10];
    if (h < 10) xr[h] = dx[n * 10 + h];
    __syncthreads();
    float acc = blin[h] + dis_emb[(size_t)dis_id[n] * HID + h];
#pragma unroll
    for (int k = 0; k < 10; ++k) acc += xr[k] * Wlin[k * HID + h];
    ushort_t hs = f2bf(acc);
    xh_dis[o] = hs;
    xl_dis[o] = f2bf(acc - bf2f(hs));
}

// ---------------- weight transpose + hi/lo split: W[K][N] f32 -> Wt[N][K] bf16
__global__ void k_trans(const float* __restrict__ W, ushort_t* __restrict__ th,
                        ushort_t* __restrict__ tl, int K, int N)
{
    __shared__ float sm[64][65];
    int n0 = blockIdx.x * 64, k0 = blockIdx.y * 64;
    int tx = threadIdx.x & 63, ty = threadIdx.x >> 6;
    for (int r = ty; r < 64; r += 4) sm[r][tx] = W[(size_t)(k0 + r) * N + n0 + tx];
    __syncthreads();
    for (int r = ty; r < 64; r += 4) {
        float v = sm[tx][r];
        ushort_t h = f2bf(v);
        float lo = v - bf2f(h);
        size_t o = (size_t)(n0 + r) * K + k0 + tx;
        th[o] = h;
        tl[o] = f2bf(lo);
    }
}

// ---------------- CSR build
__global__ void k_count(const int* __restrict__ dst, int n, int* __restrict__ cnt)
{
    int i = blockIdx.x * 256 + threadIdx.x;
    if (i < n) atomicAdd(&cnt[dst[i]], 1);
}

__global__ void k_scan(const int* __restrict__ cntA, int* __restrict__ offA,
                       const int* __restrict__ cntB, int* __restrict__ offB, int n)
{
    const int* cnt = blockIdx.x ? cntB : cntA;
    int* off = blockIdx.x ? offB : offA;
    __shared__ int sm[1024];
    __shared__ int carry;
    int tid = threadIdx.x;
    if (tid == 0) { carry = 0; off[0] = 0; }
    __syncthreads();
    for (int base = 0; base < n; base += 1024) {
        int i = base + tid;
        int v = (i < n) ? cnt[i] : 0;
        sm[tid] = v;
        __syncthreads();
        for (int o = 1; o < 1024; o <<= 1) {
            int t = (tid >= o) ? sm[tid - o] : 0;
            __syncthreads();
            sm[tid] += t;
            __syncthreads();
        }
        if (i < n) off[i + 1] = carry + sm[tid];
        int tot = sm[1023];
        __syncthreads();
        if (tid == 0) carry += tot;
        __syncthreads();
    }
}

__global__ void k_fill(const int* __restrict__ src, const int* __restrict__ dst, int n,
                       const int* __restrict__ off, int* __restrict__ cur, int* __restrict__ out)
{
    int i = blockIdx.x * 256 + threadIdx.x;
    if (i < n) {
        int d = dst[i];
        int p = atomicAdd(&cur[d], 1);
        out[off[d] + p] = src[i];
    }
}

// ---------------- fused dual mean-aggregation (hi-only output)
__global__ void k_agg2(const uint_t* __restrict__ x0, const int* __restrict__ off0,
                       const int* __restrict__ csr0, uint_t* __restrict__ o0,
                       const uint_t* __restrict__ x1, const int* __restrict__ off1,
                       const int* __restrict__ csr1, uint_t* __restrict__ o1)
{
    int d = blockIdx.x;
    const uint_t* x; const int* off; const int* csr; uint_t* ou;
    if (d < NDIS) { x = x0; off = off0; csr = csr0; ou = o0; }
    else { d -= NDIS; x = x1; off = off1; csr = csr1; ou = o1; }
    int t = threadIdx.x;
    int s = off[d], e = off[d + 1];
    float a0 = 0.f, a1 = 0.f;
    int i = s;
    for (; i + 4 <= e; i += 4) {
        int n0 = csr[i], n1 = csr[i + 1], n2 = csr[i + 2], n3 = csr[i + 3];
        uint_t v0 = x[(size_t)n0 * 128 + t];
        uint_t v1 = x[(size_t)n1 * 128 + t];
        uint_t v2 = x[(size_t)n2 * 128 + t];
        uint_t v3 = x[(size_t)n3 * 128 + t];
        a0 += bf2f(v0 & 0xffff) + bf2f(v1 & 0xffff) + bf2f(v2 & 0xffff) + bf2f(v3 & 0xffff);
        a1 += bf2f(v0 >> 16) + bf2f(v1 >> 16) + bf2f(v2 >> 16) + bf2f(v3 >> 16);
    }
    for (; i < e; ++i) {
        uint_t v = x[(size_t)csr[i] * 128 + t];
        a0 += bf2f(v & 0xffff);
        a1 += bf2f(v >> 16);
    }
    float inv = 1.f / fmaxf((float)(e - s), 1.f);
    a0 *= inv; a1 *= inv;
    ou[(size_t)d * 128 + t] = (uint_t)f2bf(a0) | ((uint_t)f2bf(a1) << 16);
}

// ---------------- pair-list MFMA GEMM
// C = act( sum_p A_p @ B_p^T + bias ). Each pair: A [M][astride] bf16 rows,
// B transposed [N][wstride] bf16. BM=64, BN=128, BK=32, 2 waves; wave = 64x64.
// G: pairs 0-2 gather A rows via ia, pairs 3+ via ib.
// FC4: fc3+fc4 fused epilogue -> out1[r] (scalar per row).
struct GJob {
    const ushort_t* prA[6];
    const ushort_t* prB[6];
    const int *ia, *ib;
    int row0;
    int astride, wstride;
    const float* bias;
    int M, N, relu, nTiles;
    ushort_t *Ch, *Cl;
    const float* w4; const float* b4; float* out1;
};

template<int NP, int SPP, int G, int FC4>
__global__ __launch_bounds__(128, 3) void k_mgemm(GJob j0, GJob j1, int blocks0)
{
    __shared__ __align__(16) ushort_t Ab[2][2048];   // [dbuf][64 x 32]
    __shared__ __align__(16) ushort_t Bb[2][4096];   // [dbuf][128 x 32]

    const int tid = threadIdx.x;
    const int lane = tid & 63;
    const int wv = tid >> 6;          // 0..1

    const int bid = blockIdx.x;
    const bool second = (bid >= blocks0);
    const GJob j = second ? j1 : j0;
    const int nblk = second ? ((int)gridDim.x - blocks0) : blocks0;
    const int tloc = second ? (bid - blocks0) : bid;
    const int t = xcd_swz(tloc, nblk);
    const int bm = ((j.nTiles == 2) ? (t >> 1) : t) * 64;
    const int bn = ((j.nTiles == 2) ? (t & 1) : 0) * 128;

    // staging geometry: thread -> 16B chunk: row q (per call-line), k-offset sk
    const int q = tid >> 2;           // 0..31
    const int sk = (tid & 3) * 8;

    int tr0 = bm + q;      if (tr0 > j.M - 1) tr0 = j.M - 1;
    int tr1 = bm + 32 + q; if (tr1 > j.M - 1) tr1 = j.M - 1;
    int ga0 = tr0, ga1 = tr1, gb0 = tr0, gb1 = tr1;
    if (G) {
        ga0 = j.ia[j.row0 + tr0]; ga1 = j.ia[j.row0 + tr1];
        gb0 = j.ib[j.row0 + tr0]; gb1 = j.ib[j.row0 + tr1];
    }
    const size_t aoffA0 = (size_t)ga0 * j.astride + sk;
    const size_t aoffA1 = (size_t)ga1 * j.astride + sk;
    const size_t aoffB0 = (size_t)gb0 * j.astride + sk;
    const size_t aoffB1 = (size_t)gb1 * j.astride + sk;
    const size_t boff = (size_t)(bn + q) * j.wstride + sk;
    const size_t ws32 = (size_t)32 * j.wstride;

    auto STAGE = [&](int p, int ks, int b) {
        const size_t k0 = (size_t)ks * 32;
        const bool useB = (G && p >= 3);
        const ushort_t* Abase = j.prA[p] + k0;
        gl_lds16(Abase + (useB ? aoffB0 : aoffA0), &Ab[b][wv * 512]);
        gl_lds16(Abase + (useB ? aoffB1 : aoffA1), &Ab[b][1024 + wv * 512]);
        const ushort_t* Bbase = j.prB[p] + boff + k0;
        gl_lds16(Bbase,            &Bb[b][wv * 512]);
        gl_lds16(Bbase + ws32,     &Bb[b][1024 + wv * 512]);
        gl_lds16(Bbase + 2 * ws32, &Bb[b][2048 + wv * 512]);
        gl_lds16(Bbase + 3 * ws32, &Bb[b][3072 + wv * 512]);
    };

    f32x4 acc[4][4] = {};
    const int arow = lane & 15;
    const int k8 = (lane >> 4) * 8;

    STAGE(0, 0, 0);

#pragma unroll
    for (int p = 0; p < NP; ++p) {
#pragma unroll
        for (int ks = 0; ks < SPP; ++ks) {
            const int s = p * SPP + ks;
            const int cur = s & 1;
            if (s + 1 < NP * SPP) {
                const int p2 = (ks + 1 < SPP) ? p : p + 1;
                const int k2 = (ks + 1 < SPP) ? ks + 1 : 0;
                STAGE(p2 < NP ? p2 : 0, k2, cur ^ 1);
                asm volatile("s_waitcnt vmcnt(6)" ::: "memory");
            } else {
                asm volatile("s_waitcnt vmcnt(0)" ::: "memory");
            }
            __builtin_amdgcn_sched_barrier(0);
            __builtin_amdgcn_s_barrier();

            s16x8 a[4];
#pragma unroll
            for (int m = 0; m < 4; ++m)
                a[m] = *(const s16x8*)&Ab[cur][(m * 16 + arow) * 32 + k8];
#pragma unroll
            for (int n = 0; n < 4; ++n) {
                s16x8 b = *(const s16x8*)&Bb[cur][(wv * 64 + n * 16 + arow) * 32 + k8];
#pragma unroll
                for (int m = 0; m < 4; ++m)
                    acc[m][n] = __builtin_amdgcn_mfma_f32_16x16x32_bf16(a[m], b, acc[m][n], 0, 0, 0);
            }
            __builtin_amdgcn_s_barrier();
        }
    }

    // epilogue: C/D layout col=lane&15, row=(lane>>4)*4+jj
    const int colC = lane & 15;
    const int rb = (lane >> 4) * 4;
    if (FC4) {
        if (wv == 0) {
#pragma unroll
            for (int m = 0; m < 4; ++m) {
#pragma unroll
                for (int jj = 0; jj < 4; ++jj) {
                    const int r = bm + m * 16 + rb + jj;
                    float v = 0.f;
#pragma unroll
                    for (int n = 0; n < 4; ++n) {
                        const int c = n * 16 + colC;
                        float e = acc[m][n][jj] + j.bias[c];
                        e = fmaxf(e, 0.f);
                        v += e * j.w4[c];
                    }
#pragma unroll
                    for (int o = 1; o < 16; o <<= 1) v += __shfl_xor(v, o);
                    if (colC == 0 && r < j.M) j.out1[r] = v + j.b4[0];
                }
            }
        }
    } else {
#pragma unroll
        for (int m = 0; m < 4; ++m) {
#pragma unroll
            for (int jj = 0; jj < 4; ++jj) {
                const int r = bm + m * 16 + rb + jj;
                if (r < j.M) {
#pragma unroll
                    for (int n = 0; n < 4; ++n) {
                        const int c = bn + wv * 64 + n * 16 + colC;
                        if (c < j.N) {
                            float v = acc[m][n][jj] + j.bias[c];
                            if (j.relu) v = fmaxf(v, 0.f);
                            ushort_t h = f2bf(v);
                            j.Ch[(size_t)r * j.N + c] = h;
                            j.Cl[(size_t)r * j.N + c] = f2bf(v - bf2f(h));
                        }
                    }
                }
            }
        }
    }
}

extern "C" void kernel_launch(void* const* d_in, const int* in_sizes, int n_in,
                              void* d_out, int out_size, void* d_ws, size_t ws_size,
                              hipStream_t stream)
{
    const int*   drug_id   = (const int*)d_in[0];
    const float* disease_x = (const float*)d_in[1];
    const int*   dis_id    = (const int*)d_in[2];
    const int*   e_mt      = (const int*)d_in[3];
    const int*   e_rev     = (const int*)d_in[4];
    const int*   e_lbl     = (const int*)d_in[5];
    const float* drug_emb  = (const float*)d_in[6];
    const float* dis_emb   = (const float*)d_in[7];
    const float* lin_w     = (const float*)d_in[8];
    const float* lin_b     = (const float*)d_in[9];
    const float* Wl_mt     = (const float*)d_in[10];
    const float* bl_mt     = (const float*)d_in[11];
    const float* Wr_mt     = (const float*)d_in[12];
    const float* Wl_rev    = (const float*)d_in[13];
    const float* bl_rev    = (const float*)d_in[14];
    const float* Wr_rev    = (const float*)d_in[15];
    const float* fc1_w = (const float*)d_in[16]; const float* fc1_b = (const float*)d_in[17];
    const float* fc2_w = (const float*)d_in[18]; const float* fc2_b = (const float*)d_in[19];
    const float* fc3_w = (const float*)d_in[20]; const float* fc3_b = (const float*)d_in[21];
    const float* fc4_w = (const float*)d_in[22]; const float* fc4_b = (const float*)d_in[23];
    float* out = (float*)d_out;

    // ---- workspace layout ----
    char* base = (char*)d_ws;
    size_t o = 0;
    auto alloc = [&](size_t bytes) { char* r = base + o; o += (bytes + 255) & ~(size_t)255; return r; };
    const size_t XB = (size_t)20000 * 256 * 2;   // one bf16 activation plane

    ushort_t* xh_dis  = (ushort_t*)alloc(XB);
    ushort_t* xl_dis  = (ushort_t*)alloc(XB);
    ushort_t* xh_drug = (ushort_t*)alloc(XB);
    ushort_t* xl_drug = (ushort_t*)alloc(XB);
    ushort_t* yh_dis  = (ushort_t*)alloc(XB);    // y planes: 4 contiguous
    ushort_t* yl_dis  = (ushort_t*)alloc(XB);
    ushort_t* yh_drug = (ushort_t*)alloc(XB);
    ushort_t* yl_drug = (ushort_t*)alloc(XB);
    ushort_t* agg_dis = (ushort_t*)alloc(XB);
    ushort_t* agg_drug= (ushort_t*)alloc(XB);
    const size_t WB = (size_t)4 * 256 * 256 * 2;
    ushort_t* wlmt_h  = (ushort_t*)alloc(WB); ushort_t* wlmt_l  = (ushort_t*)alloc(WB);
    ushort_t* wrmt_h  = (ushort_t*)alloc(WB); ushort_t* wrmt_l  = (ushort_t*)alloc(WB);
    ushort_t* wlrev_h = (ushort_t*)alloc(WB); ushort_t* wlrev_l = (ushort_t*)alloc(WB);
    ushort_t* wrrev_h = (ushort_t*)alloc(WB); ushort_t* wrrev_l = (ushort_t*)alloc(WB);
    ushort_t* fc1t_h  = (ushort_t*)alloc(512 * 256 * 2); ushort_t* fc1t_l = (ushort_t*)alloc(512 * 256 * 2);
    ushort_t* fc2t_h  = (ushort_t*)alloc(256 * 128 * 2); ushort_t* fc2t_l = (ushort_t*)alloc(256 * 128 * 2);
    ushort_t* fc3t_h  = (ushort_t*)alloc(128 * 128 * 2); ushort_t* fc3t_l = (ushort_t*)alloc(128 * 128 * 2);
    int* cnts     = (int*)alloc(80000 * 4);
    int* cnt_dis  = cnts;
    int* cnt_drug = cnts + 20000;
    int* cur_dis  = cnts + 40000;
    int* cur_drug = cnts + 60000;
    int* off_dis  = (int*)alloc(20004 * 4);
    int* off_drug = (int*)alloc(20004 * 4);
    int* csr_mt   = (int*)alloc(400000 * 4);
    int* csr_rev  = (int*)alloc(400000 * 4);
    // classifier aliases (chunk <= 40000 rows; dead buffers at that point)
    ushort_t* e1h = yh_dis;    // 40000x256 (spans yh_dis+yl_dis)
    ushort_t* e1l = yh_drug;   // 40000x256 (spans yh_drug+yl_drug)
    ushort_t* e2h = agg_dis;   // 40000x128
    ushort_t* e2l = agg_drug;  // 40000x128

    hipMemsetAsync(cnts, 0, 80000 * sizeof(int), stream);
    hipMemsetAsync(fc3t_h, 0, 128 * 128 * 2, stream);
    hipMemsetAsync(fc3t_l, 0, 128 * 128 * 2, stream);

    const float* wfam[4] = { Wl_mt, Wr_mt, Wl_rev, Wr_rev };
    ushort_t* wth[4] = { wlmt_h, wrmt_h, wlrev_h, wrrev_h };
    ushort_t* wtl[4] = { wlmt_l, wrmt_l, wlrev_l, wrrev_l };
    for (int f = 0; f < 4; ++f)
        for (int l = 0; l < NLAYERS; ++l)
            k_trans<<<dim3(4, 4), 256, 0, stream>>>(wfam[f] + (size_t)l * 65536,
                                                    wth[f] + (size_t)l * 65536,
                                                    wtl[f] + (size_t)l * 65536, 256, 256);
    k_trans<<<dim3(4, 8), 256, 0, stream>>>(fc1_w, fc1t_h, fc1t_l, 512, 256);
    k_trans<<<dim3(2, 4), 256, 0, stream>>>(fc2_w, fc2t_h, fc2t_l, 256, 128);
    k_trans<<<dim3(1, 2), 256, 0, stream>>>(fc3_w, fc3t_h, fc3t_l, 128, 64);

    k_init<<<NDRUG, HID, 0, stream>>>(drug_id, drug_emb, disease_x, lin_w, lin_b,
                                      dis_id, dis_emb, xh_drug, xl_drug, xh_dis, xl_dis);
    int nbE = (NE + 255) / 256;
    k_count<<<nbE, 256, 0, stream>>>(e_mt + NE, NE, cnt_dis);
    k_count<<<nbE, 256, 0, stream>>>(e_rev + NE, NE, cnt_drug);
    k_scan<<<2, 1024, 0, stream>>>(cnt_dis, off_dis, cnt_drug, off_drug, 20000);
    k_fill<<<nbE, 256, 0, stream>>>(e_mt, e_mt + NE, NE, off_dis, cur_dis, csr_mt);
    k_fill<<<nbE, 256, 0, stream>>>(e_rev, e_rev + NE, NE, off_drug, cur_drug, csr_rev);

    ushort_t *xdh = xh_dis, *xdl = xl_dis, *xgh = xh_drug, *xgl = xl_drug;
    ushort_t *tdh = yh_dis, *tdl = yl_dis, *tgh = yh_drug, *tgl = yl_drug;
    const int mT = (20000 + 63) / 64;       // 313
    for (int l = 0; l < NLAYERS; ++l) {
        int relu = (l < NLAYERS - 1) ? 1 : 0;
        size_t wo = (size_t)l * 65536;
        k_agg2<<<NDIS + NDRUG, 128, 0, stream>>>(
            (const uint_t*)xgh, off_dis, csr_mt, (uint_t*)agg_dis,
            (const uint_t*)xdh, off_drug, csr_rev, (uint_t*)agg_drug);
        GJob jd = { { agg_dis, agg_dis, xdh, xdh, xdl, nullptr },
                    { wlmt_h + wo, wlmt_l + wo, wrmt_h + wo, wrmt_l + wo, wrmt_h + wo, nullptr },
                    nullptr, nullptr, 0, 256, 256, bl_mt + l * HID,
                    NDIS, 256, relu, 2, tdh, tdl, nullptr, nullptr, nullptr };
        GJob jg = { { agg_drug, agg_drug, xgh, xgh, xgl, nullptr },
                    { wlrev_h + wo, wlrev_l + wo, wrrev_h + wo, wrrev_l + wo, wrrev_h + wo, nullptr },
                    nullptr, nullptr, 0, 256, 256, bl_rev + l * HID,
                    NDRUG, 256, relu, 2, tgh, tgl, nullptr, nullptr, nullptr };
        k_mgemm<5, 8, 0, 0><<<mT * 4, 128, 0, stream>>>(jd, jg, mT * 2);
        ushort_t* t;
        t = xdh; xdh = tdh; tdh = t;  t = xdl; xdl = tdl; tdl = t;
        t = xgh; xgh = tgh; tgh = t;  t = xgl; xgl = tgl; tgl = t;
    }
    // after 4 swaps x* point at the original x planes; y/agg planes are dead

    // classifier: chunks of up to 40000 label edges
    for (int c = 0; c < NEL; c += 40000) {
        int Mc = (NEL - c < 40000) ? (NEL - c) : 40000;
        int mT1 = (Mc + 63) / 64;
        GJob f1 = { { xgh, xgh, xgl, xdh, xdh, xdl },
                    { fc1t_h, fc1t_l, fc1t_h, fc1t_h + 256, fc1t_l + 256, fc1t_h + 256 },
                    e_lbl, e_lbl + NEL, c, 256, 512, fc1_b,
                    Mc, 256, 1, 2, e1h, e1l, nullptr, nullptr, nullptr };
        k_mgemm<6, 8, 1, 0><<<mT1 * 2, 128, 0, stream>>>(f1, f1, mT1 * 2);
        GJob f2 = { { e1h, e1h, e1l, nullptr, nullptr, nullptr },
                    { fc2t_h, fc2t_l, fc2t_h, nullptr, nullptr, nullptr },
                    nullptr, nullptr, 0, 256, 256, fc2_b,
                    Mc, 128, 1, 1, e2h, e2l, nullptr, nullptr, nullptr };
        k_mgemm<3, 8, 0, 0><<<mT1, 128, 0, stream>>>(f2, f2, mT1);
        GJob f3 = { { e2h, e2h, e2l, nullptr, nullptr, nullptr },
                    { fc3t_h, fc3t_l, fc3t_h, nullptr, nullptr, nullptr },
                    nullptr, nullptr, 0, 128, 128, fc3_b,
                    Mc, 64, 1, 1, nullptr, nullptr, fc4_w, fc4_b, out + c };
        k_mgemm<3, 4, 0, 1><<<mT1, 128, 0, stream>>>(f3, f3, mT1);
    }
}

// Round 7
// 881.385 us; speedup vs baseline: 1.3149x; 1.0437x over previous
//
#include <hip/hip_runtime.h>

#define HID 256
#define NDRUG 20000
#define NDIS 20000
#define NE 400000
#define NEL 100000
#define NLAYERS 4

typedef float f32x4 __attribute__((ext_vector_type(4)));
typedef short s16x8 __attribute__((ext_vector_type(8)));
typedef unsigned short ushort_t;
typedef unsigned int uint_t;

// ---- bf16 helpers (round-to-nearest-even) ----
__device__ __forceinline__ ushort_t f2bf(float f) {
    uint_t u = __float_as_uint(f);
    u += 0x7fffu + ((u >> 16) & 1u);
    return (ushort_t)(u >> 16);
}
__device__ __forceinline__ float bf2f(ushort_t h) {
    return __uint_as_float(((uint_t)h) << 16);
}

// ---- async global->LDS, 16B per lane; LDS base must be wave-uniform ----
__device__ __forceinline__ void gl_lds16(const void* g, void* l) {
    __builtin_amdgcn_global_load_lds(
        (const __attribute__((address_space(1))) void*)g,
        (__attribute__((address_space(3))) void*)l, 16, 0, 0);
}

// ---- m204 bijective XCD-chunked swizzle ----
__device__ __forceinline__ int xcd_swz(int orig, int nwg) {
    int q = nwg >> 3, r = nwg & 7;
    int x = orig & 7, i = orig >> 3;
    int start = (x < r) ? x * (q + 1) : r * (q + 1) + (x - r) * q;
    return start + i;
}

// ---------------- init
__global__ void k_init(const int* __restrict__ drug_id, const float* __restrict__ drug_emb,
                       const float* __restrict__ dx, const float* __restrict__ Wlin,
                       const float* __restrict__ blin, const int* __restrict__ dis_id,
                       const float* __restrict__ dis_emb,
                       ushort_t* __restrict__ xh_drug, ushort_t* __restrict__ xl_drug,
                       ushort_t* __restrict__ xh_dis, ushort_t* __restrict__ xl_dis)
{
    int n = blockIdx.x; int h = threadIdx.x;
    size_t o = (size_t)n * HID + h;
    float vd = drug_emb[(size_t)drug_id[n] * HID + h];
    ushort_t hd = f2bf(vd);
    xh_drug[o] = hd;
    xl_drug[o] = f2bf(vd - bf2f(hd));

    __shared__ float xr[10];
    if (h < 10) xr[h] = dx[n * 10 + h];
    __syncthreads();
    float acc = blin[h] + dis_emb[(size_t)dis_id[n] * HID + h];
#pragma unroll
    for (int k = 0; k < 10; ++k) acc += xr[k] * Wlin[k * HID + h];
    ushort_t hs = f2bf(acc);
    xh_dis[o] = hs;
    xl_dis[o] = f2bf(acc - bf2f(hs));
}

// ---------------- weight transpose + hi/lo split: W[K][N] f32 -> Wt[N][K] bf16
__global__ void k_trans(const float* __restrict__ W, ushort_t* __restrict__ th,
                        ushort_t* __restrict__ tl, int K, int N)
{
    __shared__ float sm[64][65];
    int n0 = blockIdx.x * 64, k0 = blockIdx.y * 64;
    int tx = threadIdx.x & 63, ty = threadIdx.x >> 6;
    for (int r = ty; r < 64; r += 4) sm[r][tx] = W[(size_t)(k0 + r) * N + n0 + tx];
    __syncthreads();
    for (int r = ty; r < 64; r += 4) {
        float v = sm[tx][r];
        ushort_t h = f2bf(v);
        float lo = v - bf2f(h);
        size_t o = (size_t)(n0 + r) * K + k0 + tx;
        th[o] = h;
        tl[o] = f2bf(lo);
    }
}

// ---------------- CSR build
__global__ void k_count(const int* __restrict__ dst, int n, int* __restrict__ cnt)
{
    int i = blockIdx.x * 256 + threadIdx.x;
    if (i < n) atomicAdd(&cnt[dst[i]], 1);
}

__global__ void k_scan(const int* __restrict__ cntA, int* __restrict__ offA,
                       const int* __restrict__ cntB, int* __restrict__ offB, int n)
{
    const int* cnt = blockIdx.x ? cntB : cntA;
    int* off = blockIdx.x ? offB : offA;
    __shared__ int sm[1024];
    __shared__ int carry;
    int tid = threadIdx.x;
    if (tid == 0) { carry = 0; off[0] = 0; }
    __syncthreads();
    for (int base = 0; base < n; base += 1024) {
        int i = base + tid;
        int v = (i < n) ? cnt[i] : 0;
        sm[tid] = v;
        __syncthreads();
        for (int o = 1; o < 1024; o <<= 1) {
            int t = (tid >= o) ? sm[tid - o] : 0;
            __syncthreads();
            sm[tid] += t;
            __syncthreads();
        }
        if (i < n) off[i + 1] = carry + sm[tid];
        int tot = sm[1023];
        __syncthreads();
        if (tid == 0) carry += tot;
        __syncthreads();
    }
}

__global__ void k_fill(const int* __restrict__ src, const int* __restrict__ dst, int n,
                       const int* __restrict__ off, int* __restrict__ cur, int* __restrict__ out)
{
    int i = blockIdx.x * 256 + threadIdx.x;
    if (i < n) {
        int d = dst[i];
        int p = atomicAdd(&cur[d], 1);
        out[off[d] + p] = src[i];
    }
}

// ---------------- fused dual mean-aggregation (hi-only output)
__global__ void k_agg2(const uint_t* __restrict__ x0, const int* __restrict__ off0,
                       const int* __restrict__ csr0, uint_t* __restrict__ o0,
                       const uint_t* __restrict__ x1, const int* __restrict__ off1,
                       const int* __restrict__ csr1, uint_t* __restrict__ o1)
{
    int d = blockIdx.x;
    const uint_t* x; const int* off; const int* csr; uint_t* ou;
    if (d < NDIS) { x = x0; off = off0; csr = csr0; ou = o0; }
    else { d -= NDIS; x = x1; off = off1; csr = csr1; ou = o1; }
    int t = threadIdx.x;
    int s = off[d], e = off[d + 1];
    float a0 = 0.f, a1 = 0.f;
    int i = s;
    for (; i + 4 <= e; i += 4) {
        int n0 = csr[i], n1 = csr[i + 1], n2 = csr[i + 2], n3 = csr[i + 3];
        uint_t v0 = x[(size_t)n0 * 128 + t];
        uint_t v1 = x[(size_t)n1 * 128 + t];
        uint_t v2 = x[(size_t)n2 * 128 + t];
        uint_t v3 = x[(size_t)n3 * 128 + t];
        a0 += bf2f(v0 & 0xffff) + bf2f(v1 & 0xffff) + bf2f(v2 & 0xffff) + bf2f(v3 & 0xffff);
        a1 += bf2f(v0 >> 16) + bf2f(v1 >> 16) + bf2f(v2 >> 16) + bf2f(v3 >> 16);
    }
    for (; i < e; ++i) {
        uint_t v = x[(size_t)csr[i] * 128 + t];
        a0 += bf2f(v & 0xffff);
        a1 += bf2f(v >> 16);
    }
    float inv = 1.f / fmaxf((float)(e - s), 1.f);
    a0 *= inv; a1 *= inv;
    ou[(size_t)d * 128 + t] = (uint_t)f2bf(a0) | ((uint_t)f2bf(a1) << 16);
}

// ---------------- pair-list MFMA GEMM
// C = act( sum_p A_p @ B_p^T + bias ). BM=128, BN=128, BK=32; 256 thr = 4 waves
// (2x2), wave tile 64x64. 3 LDS buffers, depth-2 prefetch, counted vmcnt(8).
// Chunk-XOR LDS swizzle (both-sides): staging pre-swizzles the GLOBAL per-lane
// address (chunk ^= (row>>1)&3, LDS write stays linear per gl_lds16 rules);
// reads XOR k8 with ((arow>>1)&3)<<3. 8-way bank conflict -> 2-way (free).
// G: pairs 0-2 gather A rows via ia, pairs 3+ via ib.
// FC4: fused fc3+fc4 epilogue -> out1[r] scalar per row (N=64 valid cols).
struct GJob {
    const ushort_t* prA[6];
    const ushort_t* prB[6];
    const int *ia, *ib;
    int row0;
    int astride, wstride;
    const float* bias;
    int M, N, relu, nTiles;
    ushort_t *Ch, *Cl;
    const float* w4; const float* b4; float* out1;
};

template<int NP, int SPP, int G, int FC4>
__global__ __launch_bounds__(256, 3) void k_mgemm(GJob j0, GJob j1, int blocks0)
{
    __shared__ __align__(16) ushort_t Ab[3][4096];   // [buf][128 x 32]
    __shared__ __align__(16) ushort_t Bb[3][4096];   // [buf][128 x 32]

    const int tid = threadIdx.x;
    const int lane = tid & 63;
    const int wv = tid >> 6;          // 0..3

    const int bid = blockIdx.x;
    const bool second = (bid >= blocks0);
    const GJob j = second ? j1 : j0;
    const int nblk = second ? ((int)gridDim.x - blocks0) : blocks0;
    const int tloc = second ? (bid - blocks0) : bid;
    const int t = xcd_swz(tloc, nblk);
    const int bm = ((j.nTiles == 2) ? (t >> 1) : t) * 128;
    const int bn = ((j.nTiles == 2) ? (t & 1) : 0) * 128;

    // staging geometry: thread -> 16B chunk; row q, swizzled k-chunk skz
    const int q = tid >> 2;                                   // 0..63
    const int skz = (((tid & 3) ^ ((tid >> 3) & 3)) << 3);    // chunk-XOR swizzle

    int tr0 = bm + q;       if (tr0 > j.M - 1) tr0 = j.M - 1;
    int tr1 = bm + 64 + q;  if (tr1 > j.M - 1) tr1 = j.M - 1;
    int ga0 = tr0, ga1 = tr1, gb0 = tr0, gb1 = tr1;
    if (G) {
        ga0 = j.ia[j.row0 + tr0]; ga1 = j.ia[j.row0 + tr1];
        gb0 = j.ib[j.row0 + tr0]; gb1 = j.ib[j.row0 + tr1];
    }
    const size_t aoffA0 = (size_t)ga0 * j.astride + skz;
    const size_t aoffA1 = (size_t)ga1 * j.astride + skz;
    const size_t aoffB0 = (size_t)gb0 * j.astride + skz;
    const size_t aoffB1 = (size_t)gb1 * j.astride + skz;
    const size_t boff = (size_t)(bn + q) * j.wstride + skz;
    const size_t ws64 = (size_t)64 * j.wstride;

    auto STAGE = [&](int p, int ks, int b) {
        const size_t k0 = (size_t)ks * 32;
        const bool useB = (G && p >= 3);
        const ushort_t* Abase = j.prA[p] + k0;
        gl_lds16(Abase + (useB ? aoffB0 : aoffA0), &Ab[b][wv * 512]);
        gl_lds16(Abase + (useB ? aoffB1 : aoffA1), &Ab[b][2048 + wv * 512]);
        const ushort_t* Bbase = j.prB[p] + boff + k0;
        gl_lds16(Bbase,        &Bb[b][wv * 512]);
        gl_lds16(Bbase + ws64, &Bb[b][2048 + wv * 512]);
    };

    f32x4 acc[4][4] = {};
    const int arow = lane & 15;
    const int k8s = ((lane >> 4) * 8) ^ (((arow >> 1) & 3) << 3);  // swizzled read
    const int wrA = (wv >> 1) * 64;
    const int wrB = (wv & 1) * 64;

    constexpr int NS = NP * SPP;
    STAGE(0, 0, 0);
    STAGE(1 / SPP, 1 % SPP, 1);

#pragma unroll
    for (int s = 0; s < NS; ++s) {
        const int cur = s % 3;
        if (s + 2 < NS) {
            STAGE((s + 2) / SPP, (s + 2) % SPP, (s + 2) % 3);
            asm volatile("s_waitcnt vmcnt(8)" ::: "memory");
        } else if (s + 1 < NS) {
            asm volatile("s_waitcnt vmcnt(4)" ::: "memory");
        } else {
            asm volatile("s_waitcnt vmcnt(0)" ::: "memory");
        }
        __builtin_amdgcn_sched_barrier(0);
        __builtin_amdgcn_s_barrier();

        s16x8 a[4];
#pragma unroll
        for (int m = 0; m < 4; ++m)
            a[m] = *(const s16x8*)&Ab[cur][(wrA + m * 16 + arow) * 32 + k8s];
#pragma unroll
        for (int n = 0; n < 4; ++n) {
            s16x8 b = *(const s16x8*)&Bb[cur][(wrB + n * 16 + arow) * 32 + k8s];
#pragma unroll
            for (int m = 0; m < 4; ++m)
                acc[m][n] = __builtin_amdgcn_mfma_f32_16x16x32_bf16(a[m], b, acc[m][n], 0, 0, 0);
        }
        __builtin_amdgcn_s_barrier();
    }

    // epilogue: C/D layout col=lane&15, row=(lane>>4)*4+jj
    const int colC = lane & 15;
    const int rb = (lane >> 4) * 4;
    if (FC4) {
        if (!(wv & 1)) {        // waves holding cols 0..63
#pragma unroll
            for (int m = 0; m < 4; ++m) {
#pragma unroll
                for (int jj = 0; jj < 4; ++jj) {
                    const int r = bm + wrA + m * 16 + rb + jj;
                    float v = 0.f;
#pragma unroll
                    for (int n = 0; n < 4; ++n) {
                        const int c = n * 16 + colC;
                        float e = acc[m][n][jj] + j.bias[c];
                        e = fmaxf(e, 0.f);
                        v += e * j.w4[c];
                    }
#pragma unroll
                    for (int o = 1; o < 16; o <<= 1) v += __shfl_xor(v, o);
                    if (colC == 0 && r < j.M) j.out1[r] = v + j.b4[0];
                }
            }
        }
    } else {
#pragma unroll
        for (int m = 0; m < 4; ++m) {
#pragma unroll
            for (int jj = 0; jj < 4; ++jj) {
                const int r = bm + wrA + m * 16 + rb + jj;
                if (r < j.M) {
#pragma unroll
                    for (int n = 0; n < 4; ++n) {
                        const int c = bn + wrB + n * 16 + colC;
                        if (c < j.N) {
                            float v = acc[m][n][jj] + j.bias[c];
                            if (j.relu) v = fmaxf(v, 0.f);
                            ushort_t h = f2bf(v);
                            j.Ch[(size_t)r * j.N + c] = h;
                            j.Cl[(size_t)r * j.N + c] = f2bf(v - bf2f(h));
                        }
                    }
                }
            }
        }
    }
}

extern "C" void kernel_launch(void* const* d_in, const int* in_sizes, int n_in,
                              void* d_out, int out_size, void* d_ws, size_t ws_size,
                              hipStream_t stream)
{
    const int*   drug_id   = (const int*)d_in[0];
    const float* disease_x = (const float*)d_in[1];
    const int*   dis_id    = (const int*)d_in[2];
    const int*   e_mt      = (const int*)d_in[3];
    const int*   e_rev     = (const int*)d_in[4];
    const int*   e_lbl     = (const int*)d_in[5];
    const float* drug_emb  = (const float*)d_in[6];
    const float* dis_emb   = (const float*)d_in[7];
    const float* lin_w     = (const float*)d_in[8];
    const float* lin_b     = (const float*)d_in[9];
    const float* Wl_mt     = (const float*)d_in[10];
    const float* bl_mt     = (const float*)d_in[11];
    const float* Wr_mt     = (const float*)d_in[12];
    const float* Wl_rev    = (const float*)d_in[13];
    const float* bl_rev    = (const float*)d_in[14];
    const float* Wr_rev    = (const float*)d_in[15];
    const float* fc1_w = (const float*)d_in[16]; const float* fc1_b = (const float*)d_in[17];
    const float* fc2_w = (const float*)d_in[18]; const float* fc2_b = (const float*)d_in[19];
    const float* fc3_w = (const float*)d_in[20]; const float* fc3_b = (const float*)d_in[21];
    const float* fc4_w = (const float*)d_in[22]; const float* fc4_b = (const float*)d_in[23];
    float* out = (float*)d_out;

    // ---- workspace layout ----
    char* base = (char*)d_ws;
    size_t o = 0;
    auto alloc = [&](size_t bytes) { char* r = base + o; o += (bytes + 255) & ~(size_t)255; return r; };
    const size_t XB = (size_t)20000 * 256 * 2;   // one bf16 activation plane

    ushort_t* xh_dis  = (ushort_t*)alloc(XB);
    ushort_t* xl_dis  = (ushort_t*)alloc(XB);
    ushort_t* xh_drug = (ushort_t*)alloc(XB);
    ushort_t* xl_drug = (ushort_t*)alloc(XB);
    ushort_t* yh_dis  = (ushort_t*)alloc(XB);    // y planes: 4 contiguous
    ushort_t* yl_dis  = (ushort_t*)alloc(XB);
    ushort_t* yh_drug = (ushort_t*)alloc(XB);
    ushort_t* yl_drug = (ushort_t*)alloc(XB);
    ushort_t* agg_dis = (ushort_t*)alloc(XB);
    ushort_t* agg_drug= (ushort_t*)alloc(XB);
    const size_t WB = (size_t)4 * 256 * 256 * 2;
    ushort_t* wlmt_h  = (ushort_t*)alloc(WB); ushort_t* wlmt_l  = (ushort_t*)alloc(WB);
    ushort_t* wrmt_h  = (ushort_t*)alloc(WB); ushort_t* wrmt_l  = (ushort_t*)alloc(WB);
    ushort_t* wlrev_h = (ushort_t*)alloc(WB); ushort_t* wlrev_l = (ushort_t*)alloc(WB);
    ushort_t* wrrev_h = (ushort_t*)alloc(WB); ushort_t* wrrev_l = (ushort_t*)alloc(WB);
    ushort_t* fc1t_h  = (ushort_t*)alloc(512 * 256 * 2); ushort_t* fc1t_l = (ushort_t*)alloc(512 * 256 * 2);
    ushort_t* fc2t_h  = (ushort_t*)alloc(256 * 128 * 2); ushort_t* fc2t_l = (ushort_t*)alloc(256 * 128 * 2);
    ushort_t* fc3t_h  = (ushort_t*)alloc(128 * 128 * 2); ushort_t* fc3t_l = (ushort_t*)alloc(128 * 128 * 2);
    int* cnts     = (int*)alloc(80000 * 4);
    int* cnt_dis  = cnts;
    int* cnt_drug = cnts + 20000;
    int* cur_dis  = cnts + 40000;
    int* cur_drug = cnts + 60000;
    int* off_dis  = (int*)alloc(20004 * 4);
    int* off_drug = (int*)alloc(20004 * 4);
    int* csr_mt   = (int*)alloc(400000 * 4);
    int* csr_rev  = (int*)alloc(400000 * 4);
    // classifier aliases (chunk <= 40000 rows; dead buffers at that point)
    ushort_t* e1h = yh_dis;    // 40000x256 (spans yh_dis+yl_dis)
    ushort_t* e1l = yh_drug;   // 40000x256 (spans yh_drug+yl_drug)
    ushort_t* e2h = agg_dis;   // 40000x128
    ushort_t* e2l = agg_drug;  // 40000x128

    hipMemsetAsync(cnts, 0, 80000 * sizeof(int), stream);
    hipMemsetAsync(fc3t_h, 0, 128 * 128 * 2, stream);
    hipMemsetAsync(fc3t_l, 0, 128 * 128 * 2, stream);

    const float* wfam[4] = { Wl_mt, Wr_mt, Wl_rev, Wr_rev };
    ushort_t* wth[4] = { wlmt_h, wrmt_h, wlrev_h, wrrev_h };
    ushort_t* wtl[4] = { wlmt_l, wrmt_l, wlrev_l, wrrev_l };
    for (int f = 0; f < 4; ++f)
        for (int l = 0; l < NLAYERS; ++l)
            k_trans<<<dim3(4, 4), 256, 0, stream>>>(wfam[f] + (size_t)l * 65536,
                                                    wth[f] + (size_t)l * 65536,
                                                    wtl[f] + (size_t)l * 65536, 256, 256);
    k_trans<<<dim3(4, 8), 256, 0, stream>>>(fc1_w, fc1t_h, fc1t_l, 512, 256);
    k_trans<<<dim3(2, 4), 256, 0, stream>>>(fc2_w, fc2t_h, fc2t_l, 256, 128);
    k_trans<<<dim3(1, 2), 256, 0, stream>>>(fc3_w, fc3t_h, fc3t_l, 128, 64);

    k_init<<<NDRUG, HID, 0, stream>>>(drug_id, drug_emb, disease_x, lin_w, lin_b,
                                      dis_id, dis_emb, xh_drug, xl_drug, xh_dis, xl_dis);
    int nbE = (NE + 255) / 256;
    k_count<<<nbE, 256, 0, stream>>>(e_mt + NE, NE, cnt_dis);
    k_count<<<nbE, 256, 0, stream>>>(e_rev + NE, NE, cnt_drug);
    k_scan<<<2, 1024, 0, stream>>>(cnt_dis, off_dis, cnt_drug, off_drug, 20000);
    k_fill<<<nbE, 256, 0, stream>>>(e_mt, e_mt + NE, NE, off_dis, cur_dis, csr_mt);
    k_fill<<<nbE, 256, 0, stream>>>(e_rev, e_rev + NE, NE, off_drug, cur_drug, csr_rev);

    ushort_t *xdh = xh_dis, *xdl = xl_dis, *xgh = xh_drug, *xgl = xl_drug;
    ushort_t *tdh = yh_dis, *tdl = yl_dis, *tgh = yh_drug, *tgl = yl_drug;
    const int mT = (20000 + 127) / 128;     // 157
    for (int l = 0; l < NLAYERS; ++l) {
        int relu = (l < NLAYERS - 1) ? 1 : 0;
        size_t wo = (size_t)l * 65536;
        k_agg2<<<NDIS + NDRUG, 128, 0, stream>>>(
            (const uint_t*)xgh, off_dis, csr_mt, (uint_t*)agg_dis,
            (const uint_t*)xdh, off_drug, csr_rev, (uint_t*)agg_drug);
        GJob jd = { { agg_dis, agg_dis, xdh, xdh, xdl, nullptr },
                    { wlmt_h + wo, wlmt_l + wo, wrmt_h + wo, wrmt_l + wo, wrmt_h + wo, nullptr },
                    nullptr, nullptr, 0, 256, 256, bl_mt + l * HID,
                    NDIS, 256, relu, 2, tdh, tdl, nullptr, nullptr, nullptr };
        GJob jg = { { agg_drug, agg_drug, xgh, xgh, xgl, nullptr },
                    { wlrev_h + wo, wlrev_l + wo, wrrev_h + wo, wrrev_l + wo, wrrev_h + wo, nullptr },
                    nullptr, nullptr, 0, 256, 256, bl_rev + l * HID,
                    NDRUG, 256, relu, 2, tgh, tgl, nullptr, nullptr, nullptr };
        k_mgemm<5, 8, 0, 0><<<mT * 4, 256, 0, stream>>>(jd, jg, mT * 2);
        ushort_t* t;
        t = xdh; xdh = tdh; tdh = t;  t = xdl; xdl = tdl; tdl = t;
        t = xgh; xgh = tgh; tgh = t;  t = xgl; xgl = tgl; tgl = t;
    }
    // after 4 swaps x* point at the original x planes; y/agg planes are dead

    // classifier: chunks of up to 40000 label edges
    for (int c = 0; c < NEL; c += 40000) {
        int Mc = (NEL - c < 40000) ? (NEL - c) : 40000;
        int mT1 = (Mc + 127) / 128;
        GJob f1 = { { xgh, xgh, xgl, xdh, xdh, xdl },
                    { fc1t_h, fc1t_l, fc1t_h, fc1t_h + 256, fc1t_l + 256, fc1t_h + 256 },
                    e_lbl, e_lbl + NEL, c, 256, 512, fc1_b,
                    Mc, 256, 1, 2, e1h, e1l, nullptr, nullptr, nullptr };
        k_mgemm<6, 8, 1, 0><<<mT1 * 2, 256, 0, stream>>>(f1, f1, mT1 * 2);
        GJob f2 = { { e1h, e1h, e1l, nullptr, nullptr, nullptr },
                    { fc2t_h, fc2t_l, fc2t_h, nullptr, nullptr, nullptr },
                    nullptr, nullptr, 0, 256, 256, fc2_b,
                    Mc, 128, 1, 1, e2h, e2l, nullptr, nullptr, nullptr };
        k_mgemm<3, 8, 0, 0><<<mT1, 256, 0, stream>>>(f2, f2, mT1);
        GJob f3 = { { e2h, e2h, e2l, nullptr, nullptr, nullptr },
                    { fc3t_h, fc3t_l, fc3t_h, nullptr, nullptr, nullptr },
                    nullptr, nullptr, 0, 128, 128, fc3_b,
                    Mc, 64, 1, 1, nullptr, nullptr, fc4_w, fc4_b, out + c };
        k_mgemm<3, 4, 0, 1><<<mT1, 256, 0, stream>>>(f3, f3, mT1);
    }
}

// Round 8
// 690.753 us; speedup vs baseline: 1.6778x; 1.2760x over previous
//
#include <hip/hip_runtime.h>

#define HID 256
#define NDRUG 20000
#define NDIS 20000
#define NE 400000
#define NEL 100000
#define NLAYERS 4

typedef float f32x4 __attribute__((ext_vector_type(4)));
typedef short s16x8 __attribute__((ext_vector_type(8)));
typedef unsigned short ushort_t;
typedef unsigned int uint_t;

// ---- bf16 helpers (round-to-nearest-even) ----
__device__ __forceinline__ ushort_t f2bf(float f) {
    uint_t u = __float_as_uint(f);
    u += 0x7fffu + ((u >> 16) & 1u);
    return (ushort_t)(u >> 16);
}
__device__ __forceinline__ float bf2f(ushort_t h) {
    return __uint_as_float(((uint_t)h) << 16);
}

// ---- async global->LDS, 16B per lane; LDS base must be wave-uniform ----
__device__ __forceinline__ void gl_lds16(const void* g, void* l) {
    __builtin_amdgcn_global_load_lds(
        (const __attribute__((address_space(1))) void*)g,
        (__attribute__((address_space(3))) void*)l, 16, 0, 0);
}

// ---- m204 bijective XCD-chunked swizzle ----
__device__ __forceinline__ int xcd_swz(int orig, int nwg) {
    int q = nwg >> 3, r = nwg & 7;
    int x = orig & 7, i = orig >> 3;
    int start = (x < r) ? x * (q + 1) : r * (q + 1) + (x - r) * q;
    return start + i;
}

// ---------------- init: x planes bf16 hi-only
__global__ void k_init(const int* __restrict__ drug_id, const float* __restrict__ drug_emb,
                       const float* __restrict__ dx, const float* __restrict__ Wlin,
                       const float* __restrict__ blin, const int* __restrict__ dis_id,
                       const float* __restrict__ dis_emb,
                       ushort_t* __restrict__ x_drug, ushort_t* __restrict__ x_dis)
{
    int n = blockIdx.x; int h = threadIdx.x;
    size_t o = (size_t)n * HID + h;
    x_drug[o] = f2bf(drug_emb[(size_t)drug_id[n] * HID + h]);

    __shared__ float xr[10];
    if (h < 10) xr[h] = dx[n * 10 + h];
    __syncthreads();
    float acc = blin[h] + dis_emb[(size_t)dis_id[n] * HID + h];
#pragma unroll
    for (int k = 0; k < 10; ++k) acc += xr[k] * Wlin[k * HID + h];
    x_dis[o] = f2bf(acc);
}

// ---------------- fused weight transpose + hi/lo split, ALL weights, 1 launch
// blocks 0..255: layer fams (fam=bid>>6, layer=(bid>>4)&3, 16 tiles of 64x64)
// 256..287: fc1 (K=512,N=256); 288..295: fc2 (K=256,N=128); 296..297: fc3 (K=128,N=64)
struct TP { const float* src[7]; ushort_t* th[7]; ushort_t* tl[7]; };
__global__ void k_trans_all(TP tp)
{
    __shared__ float sm[64][65];
    int bid = blockIdx.x;
    const float* W; ushort_t *pth, *ptl; int K, N, n0, k0;
    if (bid < 256) {
        int fam = bid >> 6, l = (bid >> 4) & 3, t = bid & 15;
        W = tp.src[fam] + (size_t)l * 65536;
        pth = tp.th[fam] + (size_t)l * 65536;
        ptl = tp.tl[fam] + (size_t)l * 65536;
        K = 256; N = 256; n0 = (t & 3) * 64; k0 = (t >> 2) * 64;
    } else if (bid < 288) {
        int t = bid - 256; W = tp.src[4]; pth = tp.th[4]; ptl = tp.tl[4];
        K = 512; N = 256; n0 = (t & 3) * 64; k0 = (t >> 2) * 64;
    } else if (bid < 296) {
        int t = bid - 288; W = tp.src[5]; pth = tp.th[5]; ptl = tp.tl[5];
        K = 256; N = 128; n0 = (t & 1) * 64; k0 = (t >> 1) * 64;
    } else {
        int t = bid - 296; W = tp.src[6]; pth = tp.th[6]; ptl = tp.tl[6];
        K = 128; N = 64; n0 = 0; k0 = t * 64;
    }
    int tx = threadIdx.x & 63, ty = threadIdx.x >> 6;
    for (int r = ty; r < 64; r += 4) sm[r][tx] = W[(size_t)(k0 + r) * N + n0 + tx];
    __syncthreads();
    for (int r = ty; r < 64; r += 4) {
        float v = sm[tx][r];
        ushort_t h = f2bf(v);
        size_t o = (size_t)(n0 + r) * K + k0 + tx;
        pth[o] = h;
        ptl[o] = f2bf(v - bf2f(h));
    }
}

// ---------------- CSR build
__global__ void k_count(const int* __restrict__ dst, int n, int* __restrict__ cnt)
{
    int i = blockIdx.x * 256 + threadIdx.x;
    if (i < n) atomicAdd(&cnt[dst[i]], 1);
}

__global__ void k_scan(const int* __restrict__ cntA, int* __restrict__ offA,
                       const int* __restrict__ cntB, int* __restrict__ offB, int n)
{
    const int* cnt = blockIdx.x ? cntB : cntA;
    int* off = blockIdx.x ? offB : offA;
    __shared__ int sm[1024];
    __shared__ int carry;
    int tid = threadIdx.x;
    if (tid == 0) { carry = 0; off[0] = 0; }
    __syncthreads();
    for (int base = 0; base < n; base += 1024) {
        int i = base + tid;
        int v = (i < n) ? cnt[i] : 0;
        sm[tid] = v;
        __syncthreads();
        for (int o = 1; o < 1024; o <<= 1) {
            int t = (tid >= o) ? sm[tid - o] : 0;
            __syncthreads();
            sm[tid] += t;
            __syncthreads();
        }
        if (i < n) off[i + 1] = carry + sm[tid];
        int tot = sm[1023];
        __syncthreads();
        if (tid == 0) carry += tot;
        __syncthreads();
    }
}

__global__ void k_fill(const int* __restrict__ src, const int* __restrict__ dst, int n,
                       const int* __restrict__ off, int* __restrict__ cur, int* __restrict__ out)
{
    int i = blockIdx.x * 256 + threadIdx.x;
    if (i < n) {
        int d = dst[i];
        int p = atomicAdd(&cur[d], 1);
        out[off[d] + p] = src[i];
    }
}

// ---------------- fused dual mean-aggregation (bf16 in/out)
__global__ void k_agg2(const uint_t* __restrict__ x0, const int* __restrict__ off0,
                       const int* __restrict__ csr0, uint_t* __restrict__ o0,
                       const uint_t* __restrict__ x1, const int* __restrict__ off1,
                       const int* __restrict__ csr1, uint_t* __restrict__ o1)
{
    int d = blockIdx.x;
    const uint_t* x; const int* off; const int* csr; uint_t* ou;
    if (d < NDIS) { x = x0; off = off0; csr = csr0; ou = o0; }
    else { d -= NDIS; x = x1; off = off1; csr = csr1; ou = o1; }
    int t = threadIdx.x;
    int s = off[d], e = off[d + 1];
    float a0 = 0.f, a1 = 0.f;
    int i = s;
    for (; i + 4 <= e; i += 4) {
        int n0 = csr[i], n1 = csr[i + 1], n2 = csr[i + 2], n3 = csr[i + 3];
        uint_t v0 = x[(size_t)n0 * 128 + t];
        uint_t v1 = x[(size_t)n1 * 128 + t];
        uint_t v2 = x[(size_t)n2 * 128 + t];
        uint_t v3 = x[(size_t)n3 * 128 + t];
        a0 += bf2f(v0 & 0xffff) + bf2f(v1 & 0xffff) + bf2f(v2 & 0xffff) + bf2f(v3 & 0xffff);
        a1 += bf2f(v0 >> 16) + bf2f(v1 >> 16) + bf2f(v2 >> 16) + bf2f(v3 >> 16);
    }
    for (; i < e; ++i) {
        uint_t v = x[(size_t)csr[i] * 128 + t];
        a0 += bf2f(v & 0xffff);
        a1 += bf2f(v >> 16);
    }
    float inv = 1.f / fmaxf((float)(e - s), 1.f);
    a0 *= inv; a1 *= inv;
    ou[(size_t)d * 128 + t] = (uint_t)f2bf(a0) | ((uint_t)f2bf(a1) << 16);
}

// ---------------- A-share alternating-B MFMA GEMM
// C = act( sum_a A_a @ (Bh_a + Bl_a)^T + bias ). BM=128, BN=128; 4 waves (2x2),
// wave tile 64x64. Steps alternate: even s stages A-chunk + Bh, odd stages Bl
// only; A fragments persist in registers across the odd step. A: 2 LDS bufs,
// B: 3 bufs (depth-2 prefetch). Uniform s_waitcnt vmcnt(6) (two stages in
// flight: 4+2 or 2+4 loads). Chunk-XOR LDS swizzle both-sides (0 conflicts).
// G: stage0 gathers A rows via ia, stage1 via ib. FC4: fused fc3+fc4 epilogue.
struct GJob {
    const ushort_t* A[2];
    const ushort_t* Bh[2];
    const ushort_t* Bl[2];
    const int *ia, *ib;
    int row0;
    int astride, wstride;
    const float* bias;
    int M, N, relu, nTiles;
    ushort_t* C;
    const float* w4; const float* b4; float* out1;
};

template<int NA, int SPP, int G, int FC4>
__global__ __launch_bounds__(256, 3) void k_mgemm(GJob j0, GJob j1, int blocks0)
{
    __shared__ __align__(16) ushort_t Ab[2][4096];   // [slot][128 x 32]
    __shared__ __align__(16) ushort_t Bb[3][4096];   // [slot][128 x 32]

    const int tid = threadIdx.x;
    const int lane = tid & 63;
    const int wv = tid >> 6;

    const int bid = blockIdx.x;
    const bool second = (bid >= blocks0);
    const GJob j = second ? j1 : j0;
    const int nblk = second ? ((int)gridDim.x - blocks0) : blocks0;
    const int tloc = second ? (bid - blocks0) : bid;
    const int t = xcd_swz(tloc, nblk);
    const int bm = ((j.nTiles == 2) ? (t >> 1) : t) * 128;
    const int bn = ((j.nTiles == 2) ? (t & 1) : 0) * 128;

    // staging geometry: thread -> 16B chunk; row q, chunk-XOR swizzled k-offset
    const int q = tid >> 2;                                   // 0..63
    const int skz = (((tid & 3) ^ ((tid >> 3) & 3)) << 3);

    int tr0 = bm + q;       if (tr0 > j.M - 1) tr0 = j.M - 1;
    int tr1 = bm + 64 + q;  if (tr1 > j.M - 1) tr1 = j.M - 1;
    size_t aoff0[2], aoff1[2];
    if (G) {
        int g00 = j.ia[j.row0 + tr0], g01 = j.ia[j.row0 + tr1];
        int g10 = j.ib[j.row0 + tr0], g11 = j.ib[j.row0 + tr1];
        aoff0[0] = (size_t)g00 * j.astride + skz;
        aoff1[0] = (size_t)g01 * j.astride + skz;
        aoff0[1] = (size_t)g10 * j.astride + skz;
        aoff1[1] = (size_t)g11 * j.astride + skz;
    } else {
        aoff0[0] = aoff0[1] = (size_t)tr0 * j.astride + skz;
        aoff1[0] = aoff1[1] = (size_t)tr1 * j.astride + skz;
    }
    const size_t boff = (size_t)(bn + q) * j.wstride + skz;
    const size_t ws64 = (size_t)64 * j.wstride;

    // u = A-chunk index = step>>1; a = u/SPP (A-stage), ks = u%SPP (k-chunk)
    auto STAGE_A = [&](int u, int slot) {
        const int a = u / SPP, ks = u % SPP;
        const ushort_t* Ap = j.A[a] + (size_t)ks * 32;
        gl_lds16(Ap + aoff0[a], &Ab[slot][wv * 512]);
        gl_lds16(Ap + aoff1[a], &Ab[slot][2048 + wv * 512]);
    };
    auto STAGE_B = [&](int s2, int slot) {
        const int u = s2 >> 1, a = u / SPP, ks = u % SPP, h = s2 & 1;
        const ushort_t* Bp = (h ? j.Bl[a] : j.Bh[a]) + boff + (size_t)ks * 32;
        gl_lds16(Bp,        &Bb[slot][wv * 512]);
        gl_lds16(Bp + ws64, &Bb[slot][2048 + wv * 512]);
    };

    f32x4 acc[4][4] = {};
    s16x8 a_frag[4];
    const int arow = lane & 15;
    const int k8s = ((lane >> 4) * 8) ^ (((arow >> 1) & 3) << 3);
    const int wrA = (wv >> 1) * 64;
    const int wrB = (wv & 1) * 64;

    constexpr int NS = NA * SPP * 2;
    STAGE_A(0, 0); STAGE_B(0, 0);     // 4 loads (for step 0)
    STAGE_B(1, 1);                    // 2 loads (for step 1)

#pragma unroll
    for (int s = 0; s < NS; ++s) {
        const int bslot = s % 3;
        if (s + 2 < NS) {
            if (((s + 2) & 1) == 0) STAGE_A((s + 2) >> 1, ((s + 2) >> 1) & 1);
            STAGE_B(s + 2, (s + 2) % 3);
            asm volatile("s_waitcnt vmcnt(6)" ::: "memory");
        } else if (s + 1 < NS) {
            asm volatile("s_waitcnt vmcnt(2)" ::: "memory");
        } else {
            asm volatile("s_waitcnt vmcnt(0)" ::: "memory");
        }
        __builtin_amdgcn_sched_barrier(0);
        __builtin_amdgcn_s_barrier();

        if ((s & 1) == 0) {
            const int aslot = (s >> 1) & 1;
#pragma unroll
            for (int m = 0; m < 4; ++m)
                a_frag[m] = *(const s16x8*)&Ab[aslot][(wrA + m * 16 + arow) * 32 + k8s];
        }
#pragma unroll
        for (int n = 0; n < 4; ++n) {
            s16x8 b = *(const s16x8*)&Bb[bslot][(wrB + n * 16 + arow) * 32 + k8s];
#pragma unroll
            for (int m = 0; m < 4; ++m)
                acc[m][n] = __builtin_amdgcn_mfma_f32_16x16x32_bf16(a_frag[m], b, acc[m][n], 0, 0, 0);
        }
        __builtin_amdgcn_s_barrier();
    }

    // epilogue: C/D layout col=lane&15, row=(lane>>4)*4+jj
    const int colC = lane & 15;
    const int rb = (lane >> 4) * 4;
    if (FC4) {
        if (!(wv & 1)) {        // waves holding cols 0..63
#pragma unroll
            for (int m = 0; m < 4; ++m) {
#pragma unroll
                for (int jj = 0; jj < 4; ++jj) {
                    const int r = bm + wrA + m * 16 + rb + jj;
                    float v = 0.f;
#pragma unroll
                    for (int n = 0; n < 4; ++n) {
                        const int c = n * 16 + colC;
                        float e = acc[m][n][jj] + j.bias[c];
                        e = fmaxf(e, 0.f);
                        v += e * j.w4[c];
                    }
#pragma unroll
                    for (int o = 1; o < 16; o <<= 1) v += __shfl_xor(v, o);
                    if (colC == 0 && r < j.M) j.out1[r] = v + j.b4[0];
                }
            }
        }
    } else {
#pragma unroll
        for (int m = 0; m < 4; ++m) {
#pragma unroll
            for (int jj = 0; jj < 4; ++jj) {
                const int r = bm + wrA + m * 16 + rb + jj;
                if (r < j.M) {
#pragma unroll
                    for (int n = 0; n < 4; ++n) {
                        const int c = bn + wrB + n * 16 + colC;
                        if (c < j.N) {
                            float v = acc[m][n][jj] + j.bias[c];
                            if (j.relu) v = fmaxf(v, 0.f);
                            j.C[(size_t)r * j.N + c] = f2bf(v);
                        }
                    }
                }
            }
        }
    }
}

extern "C" void kernel_launch(void* const* d_in, const int* in_sizes, int n_in,
                              void* d_out, int out_size, void* d_ws, size_t ws_size,
                              hipStream_t stream)
{
    const int*   drug_id   = (const int*)d_in[0];
    const float* disease_x = (const float*)d_in[1];
    const int*   dis_id    = (const int*)d_in[2];
    const int*   e_mt      = (const int*)d_in[3];
    const int*   e_rev     = (const int*)d_in[4];
    const int*   e_lbl     = (const int*)d_in[5];
    const float* drug_emb  = (const float*)d_in[6];
    const float* dis_emb   = (const float*)d_in[7];
    const float* lin_w     = (const float*)d_in[8];
    const float* lin_b     = (const float*)d_in[9];
    const float* Wl_mt     = (const float*)d_in[10];
    const float* bl_mt     = (const float*)d_in[11];
    const float* Wr_mt     = (const float*)d_in[12];
    const float* Wl_rev    = (const float*)d_in[13];
    const float* bl_rev    = (const float*)d_in[14];
    const float* Wr_rev    = (const float*)d_in[15];
    const float* fc1_w = (const float*)d_in[16]; const float* fc1_b = (const float*)d_in[17];
    const float* fc2_w = (const float*)d_in[18]; const float* fc2_b = (const float*)d_in[19];
    const float* fc3_w = (const float*)d_in[20]; const float* fc3_b = (const float*)d_in[21];
    const float* fc4_w = (const float*)d_in[22]; const float* fc4_b = (const float*)d_in[23];
    float* out = (float*)d_out;

    // ---- workspace layout ----
    char* base = (char*)d_ws;
    size_t o = 0;
    auto alloc = [&](size_t bytes) { char* r = base + o; o += (bytes + 255) & ~(size_t)255; return r; };
    const size_t XB = (size_t)20000 * 256 * 2;   // one bf16 activation plane

    ushort_t* x_dis   = (ushort_t*)alloc(XB);
    ushort_t* x_drug  = (ushort_t*)alloc(XB);
    ushort_t* y_dis   = (ushort_t*)alloc(XB);    // y_dis,y_drug contiguous (e1 alias)
    ushort_t* y_drug  = (ushort_t*)alloc(XB);
    ushort_t* agg_dis = (ushort_t*)alloc(XB);
    ushort_t* agg_drug= (ushort_t*)alloc(XB);
    const size_t WB = (size_t)4 * 256 * 256 * 2;
    ushort_t* wlmt_h  = (ushort_t*)alloc(WB); ushort_t* wlmt_l  = (ushort_t*)alloc(WB);
    ushort_t* wrmt_h  = (ushort_t*)alloc(WB); ushort_t* wrmt_l  = (ushort_t*)alloc(WB);
    ushort_t* wlrev_h = (ushort_t*)alloc(WB); ushort_t* wlrev_l = (ushort_t*)alloc(WB);
    ushort_t* wrrev_h = (ushort_t*)alloc(WB); ushort_t* wrrev_l = (ushort_t*)alloc(WB);
    ushort_t* fc1t_h  = (ushort_t*)alloc(512 * 256 * 2); ushort_t* fc1t_l = (ushort_t*)alloc(512 * 256 * 2);
    ushort_t* fc2t_h  = (ushort_t*)alloc(256 * 128 * 2); ushort_t* fc2t_l = (ushort_t*)alloc(256 * 128 * 2);
    ushort_t* fc3t_h  = (ushort_t*)alloc(128 * 128 * 2); ushort_t* fc3t_l = (ushort_t*)alloc(128 * 128 * 2);
    int* cnts     = (int*)alloc(80000 * 4);
    int* cnt_dis  = cnts;
    int* cnt_drug = cnts + 20000;
    int* cur_dis  = cnts + 40000;
    int* cur_drug = cnts + 60000;
    int* off_dis  = (int*)alloc(20004 * 4);
    int* off_drug = (int*)alloc(20004 * 4);
    int* csr_mt   = (int*)alloc(400000 * 4);
    int* csr_rev  = (int*)alloc(400000 * 4);
    // classifier aliases (chunk <= 40000 rows; dead buffers at that point)
    ushort_t* e1 = y_dis;      // 40000x256 bf16 (spans y_dis+y_drug)
    ushort_t* e2 = agg_dis;    // 40000x128 bf16

    hipMemsetAsync(cnts, 0, 80000 * sizeof(int), stream);
    hipMemsetAsync(fc3t_h, 0, 128 * 128 * 2, stream);
    hipMemsetAsync(fc3t_l, 0, 128 * 128 * 2, stream);

    TP tp;
    tp.src[0] = Wl_mt;  tp.th[0] = wlmt_h;  tp.tl[0] = wlmt_l;
    tp.src[1] = Wr_mt;  tp.th[1] = wrmt_h;  tp.tl[1] = wrmt_l;
    tp.src[2] = Wl_rev; tp.th[2] = wlrev_h; tp.tl[2] = wlrev_l;
    tp.src[3] = Wr_rev; tp.th[3] = wrrev_h; tp.tl[3] = wrrev_l;
    tp.src[4] = fc1_w;  tp.th[4] = fc1t_h;  tp.tl[4] = fc1t_l;
    tp.src[5] = fc2_w;  tp.th[5] = fc2t_h;  tp.tl[5] = fc2t_l;
    tp.src[6] = fc3_w;  tp.th[6] = fc3t_h;  tp.tl[6] = fc3t_l;
    k_trans_all<<<298, 256, 0, stream>>>(tp);

    k_init<<<NDRUG, HID, 0, stream>>>(drug_id, drug_emb, disease_x, lin_w, lin_b,
                                      dis_id, dis_emb, x_drug, x_dis);
    int nbE = (NE + 255) / 256;
    k_count<<<nbE, 256, 0, stream>>>(e_mt + NE, NE, cnt_dis);
    k_count<<<nbE, 256, 0, stream>>>(e_rev + NE, NE, cnt_drug);
    k_scan<<<2, 1024, 0, stream>>>(cnt_dis, off_dis, cnt_drug, off_drug, 20000);
    k_fill<<<nbE, 256, 0, stream>>>(e_mt, e_mt + NE, NE, off_dis, cur_dis, csr_mt);
    k_fill<<<nbE, 256, 0, stream>>>(e_rev, e_rev + NE, NE, off_drug, cur_drug, csr_rev);

    ushort_t *xd = x_dis, *xg = x_drug;
    ushort_t *td = y_dis, *tg = y_drug;
    const int mT = (20000 + 127) / 128;     // 157
    for (int l = 0; l < NLAYERS; ++l) {
        int relu = (l < NLAYERS - 1) ? 1 : 0;
        size_t wo = (size_t)l * 65536;
        k_agg2<<<NDIS + NDRUG, 128, 0, stream>>>(
            (const uint_t*)xg, off_dis, csr_mt, (uint_t*)agg_dis,
            (const uint_t*)xd, off_drug, csr_rev, (uint_t*)agg_drug);
        GJob jd = { { agg_dis, xd }, { wlmt_h + wo, wrmt_h + wo }, { wlmt_l + wo, wrmt_l + wo },
                    nullptr, nullptr, 0, 256, 256, bl_mt + l * HID,
                    NDIS, 256, relu, 2, td, nullptr, nullptr, nullptr };
        GJob jg = { { agg_drug, xg }, { wlrev_h + wo, wrrev_h + wo }, { wlrev_l + wo, wrrev_l + wo },
                    nullptr, nullptr, 0, 256, 256, bl_rev + l * HID,
                    NDRUG, 256, relu, 2, tg, nullptr, nullptr, nullptr };
        k_mgemm<2, 8, 0, 0><<<mT * 4, 256, 0, stream>>>(jd, jg, mT * 2);
        ushort_t* t;
        t = xd; xd = td; td = t;
        t = xg; xg = tg; tg = t;
    }
    // after 4 swaps x* point at the original x planes; y/agg planes are dead

    // classifier: chunks of up to 40000 label edges
    for (int c = 0; c < NEL; c += 40000) {
        int Mc = (NEL - c < 40000) ? (NEL - c) : 40000;
        int mT1 = (Mc + 127) / 128;
        GJob f1 = { { xg, xd }, { fc1t_h, fc1t_h + 256 }, { fc1t_l, fc1t_l + 256 },
                    e_lbl, e_lbl + NEL, c, 256, 512, fc1_b,
                    Mc, 256, 1, 2, e1, nullptr, nullptr, nullptr };
        k_mgemm<2, 8, 1, 0><<<mT1 * 2, 256, 0, stream>>>(f1, f1, mT1 * 2);
        GJob f2 = { { e1, nullptr }, { fc2t_h, nullptr }, { fc2t_l, nullptr },
                    nullptr, nullptr, 0, 256, 256, fc2_b,
                    Mc, 128, 1, 1, e2, nullptr, nullptr, nullptr };
        k_mgemm<1, 8, 0, 0><<<mT1, 256, 0, stream>>>(f2, f2, mT1);
        GJob f3 = { { e2, nullptr }, { fc3t_h, nullptr }, { fc3t_l, nullptr },
                    nullptr, nullptr, 0, 128, 128, fc3_b,
                    Mc, 64, 1, 1, nullptr, fc4_w, fc4_b, out + c };
        k_mgemm<1, 4, 0, 1><<<mT1, 256, 0, stream>>>(f3, f3, mT1);
    }
}

// Round 9
// 610.237 us; speedup vs baseline: 1.8992x; 1.1319x over previous
//
#include <hip/hip_runtime.h>

#define HID 256
#define NDRUG 20000
#define NDIS 20000
#define NE 400000
#define NEL 100000
#define NLAYERS 4

typedef float f32x4 __attribute__((ext_vector_type(4)));
typedef short s16x8 __attribute__((ext_vector_type(8)));
typedef unsigned short ushort_t;
typedef unsigned int uint_t;

// ---- bf16 helpers (round-to-nearest-even) ----
__device__ __forceinline__ ushort_t f2bf(float f) {
    uint_t u = __float_as_uint(f);
    u += 0x7fffu + ((u >> 16) & 1u);
    return (ushort_t)(u >> 16);
}
__device__ __forceinline__ float bf2f(ushort_t h) {
    return __uint_as_float(((uint_t)h) << 16);
}

// ---- async global->LDS, 16B per lane; LDS base must be wave-uniform ----
__device__ __forceinline__ void gl_lds16(const void* g, void* l) {
    __builtin_amdgcn_global_load_lds(
        (const __attribute__((address_space(1))) void*)g,
        (__attribute__((address_space(3))) void*)l, 16, 0, 0);
}

// ---- m204 bijective XCD-chunked swizzle ----
__device__ __forceinline__ int xcd_swz(int orig, int nwg) {
    int q = nwg >> 3, r = nwg & 7;
    int x = orig & 7, i = orig >> 3;
    int start = (x < r) ? x * (q + 1) : r * (q + 1) + (x - r) * q;
    return start + i;
}

// ---------------- init: x planes bf16 hi-only
__global__ void k_init(const int* __restrict__ drug_id, const float* __restrict__ drug_emb,
                       const float* __restrict__ dx, const float* __restrict__ Wlin,
                       const float* __restrict__ blin, const int* __restrict__ dis_id,
                       const float* __restrict__ dis_emb,
                       ushort_t* __restrict__ x_drug, ushort_t* __restrict__ x_dis)
{
    int n = blockIdx.x; int h = threadIdx.x;
    size_t o = (size_t)n * HID + h;
    x_drug[o] = f2bf(drug_emb[(size_t)drug_id[n] * HID + h]);

    __shared__ float xr[10];
    if (h < 10) xr[h] = dx[n * 10 + h];
    __syncthreads();
    float acc = blin[h] + dis_emb[(size_t)dis_id[n] * HID + h];
#pragma unroll
    for (int k = 0; k < 10; ++k) acc += xr[k] * Wlin[k * HID + h];
    x_dis[o] = f2bf(acc);
}

// ---------------- fused weight transpose + hi/lo split, ALL weights, 1 launch
struct TP { const float* src[7]; ushort_t* th[7]; ushort_t* tl[7]; };
__global__ void k_trans_all(TP tp)
{
    __shared__ float sm[64][65];
    int bid = blockIdx.x;
    const float* W; ushort_t *pth, *ptl; int K, N, n0, k0;
    if (bid < 256) {
        int fam = bid >> 6, l = (bid >> 4) & 3, t = bid & 15;
        W = tp.src[fam] + (size_t)l * 65536;
        pth = tp.th[fam] + (size_t)l * 65536;
        ptl = tp.tl[fam] + (size_t)l * 65536;
        K = 256; N = 256; n0 = (t & 3) * 64; k0 = (t >> 2) * 64;
    } else if (bid < 288) {
        int t = bid - 256; W = tp.src[4]; pth = tp.th[4]; ptl = tp.tl[4];
        K = 512; N = 256; n0 = (t & 3) * 64; k0 = (t >> 2) * 64;
    } else if (bid < 296) {
        int t = bid - 288; W = tp.src[5]; pth = tp.th[5]; ptl = tp.tl[5];
        K = 256; N = 128; n0 = (t & 1) * 64; k0 = (t >> 1) * 64;
    } else {
        int t = bid - 296; W = tp.src[6]; pth = tp.th[6]; ptl = tp.tl[6];
        K = 128; N = 64; n0 = 0; k0 = t * 64;
    }
    int tx = threadIdx.x & 63, ty = threadIdx.x >> 6;
    for (int r = ty; r < 64; r += 4) sm[r][tx] = W[(size_t)(k0 + r) * N + n0 + tx];
    __syncthreads();
    for (int r = ty; r < 64; r += 4) {
        float v = sm[tx][r];
        ushort_t h = f2bf(v);
        size_t o = (size_t)(n0 + r) * K + k0 + tx;
        pth[o] = h;
        ptl[o] = f2bf(v - bf2f(h));
    }
}

// ---------------- CSR build
__global__ void k_count(const int* __restrict__ dst, int n, int* __restrict__ cnt)
{
    int i = blockIdx.x * 256 + threadIdx.x;
    if (i < n) atomicAdd(&cnt[dst[i]], 1);
}

__global__ void k_scan(const int* __restrict__ cntA, int* __restrict__ offA,
                       const int* __restrict__ cntB, int* __restrict__ offB, int n)
{
    const int* cnt = blockIdx.x ? cntB : cntA;
    int* off = blockIdx.x ? offB : offA;
    __shared__ int sm[1024];
    __shared__ int carry;
    int tid = threadIdx.x;
    if (tid == 0) { carry = 0; off[0] = 0; }
    __syncthreads();
    for (int base = 0; base < n; base += 1024) {
        int i = base + tid;
        int v = (i < n) ? cnt[i] : 0;
        sm[tid] = v;
        __syncthreads();
        for (int o = 1; o < 1024; o <<= 1) {
            int t = (tid >= o) ? sm[tid - o] : 0;
            __syncthreads();
            sm[tid] += t;
            __syncthreads();
        }
        if (i < n) off[i + 1] = carry + sm[tid];
        int tot = sm[1023];
        __syncthreads();
        if (tid == 0) carry += tot;
        __syncthreads();
    }
}

__global__ void k_fill(const int* __restrict__ src, const int* __restrict__ dst, int n,
                       const int* __restrict__ off, int* __restrict__ cur, int* __restrict__ out)
{
    int i = blockIdx.x * 256 + threadIdx.x;
    if (i < n) {
        int d = dst[i];
        int p = atomicAdd(&cur[d], 1);
        out[off[d] + p] = src[i];
    }
}

// ---------------- fused dual mean-aggregation (bf16 in/out), unroll-8
__global__ void k_agg2(const uint_t* __restrict__ x0, const int* __restrict__ off0,
                       const int* __restrict__ csr0, uint_t* __restrict__ o0,
                       const uint_t* __restrict__ x1, const int* __restrict__ off1,
                       const int* __restrict__ csr1, uint_t* __restrict__ o1)
{
    int d = blockIdx.x;
    const uint_t* x; const int* off; const int* csr; uint_t* ou;
    if (d < NDIS) { x = x0; off = off0; csr = csr0; ou = o0; }
    else { d -= NDIS; x = x1; off = off1; csr = csr1; ou = o1; }
    int t = threadIdx.x;
    int s = off[d], e = off[d + 1];
    float a0 = 0.f, a1 = 0.f;
    int i = s;
    for (; i + 8 <= e; i += 8) {
        uint_t v[8];
#pragma unroll
        for (int u = 0; u < 8; ++u) v[u] = x[(size_t)csr[i + u] * 128 + t];
#pragma unroll
        for (int u = 0; u < 8; ++u) {
            a0 += bf2f(v[u] & 0xffff);
            a1 += bf2f(v[u] >> 16);
        }
    }
    for (; i < e; ++i) {
        uint_t v = x[(size_t)csr[i] * 128 + t];
        a0 += bf2f(v & 0xffff);
        a1 += bf2f(v >> 16);
    }
    float inv = 1.f / fmaxf((float)(e - s), 1.f);
    a0 *= inv; a1 *= inv;
    ou[(size_t)d * 128 + t] = (uint_t)f2bf(a0) | ((uint_t)f2bf(a1) << 16);
}

// ---------------- A-share alternating-B MFMA GEMM, 1-barrier pipeline
// C = act( sum_a A_a @ (Bh_a + Bl_a)^T + bias ). BM=128, BN=128; 4 waves (2x2),
// wave tile 64x64. Even step s: new A-chunk (regs persist through odd step) +
// Bh; odd step: Bl. A: 2 slots, B: 3 slots, depth-2 prefetch. Step structure:
// s_barrier -> STAGE(s+2) -> counted vmcnt -> ds_read+MFMA (setprio 1). The
// end-of-step barrier is dropped: with 3-deep B/2-deep A, a STAGE issued after
// barrier(s) can only overwrite slots whose readers all completed before
// barrier(s) (ds_reads are consumed by MFMAs before each wave reaches it).
// Chunk-XOR LDS swizzle both-sides (0 bank conflicts).
struct GJob {
    const ushort_t* A[2];
    const ushort_t* Bh[2];
    const ushort_t* Bl[2];
    const int *ia, *ib;
    int row0;
    int astride, wstride;
    const float* bias;
    int M, N, relu, nTiles;
    ushort_t* C;
    const float* w4; const float* b4; float* out1;
};

template<int NA, int SPP, int G, int FC4>
__global__ __launch_bounds__(256, 4) void k_mgemm(GJob j0, GJob j1, int blocks0)
{
    __shared__ __align__(16) ushort_t Ab[2][4096];   // [slot][128 x 32]
    __shared__ __align__(16) ushort_t Bb[3][4096];   // [slot][128 x 32]

    const int tid = threadIdx.x;
    const int lane = tid & 63;
    const int wv = tid >> 6;

    const int bid = blockIdx.x;
    const bool second = (bid >= blocks0);
    const GJob j = second ? j1 : j0;
    const int nblk = second ? ((int)gridDim.x - blocks0) : blocks0;
    const int tloc = second ? (bid - blocks0) : bid;
    const int t = xcd_swz(tloc, nblk);
    const int bm = ((j.nTiles == 2) ? (t >> 1) : t) * 128;
    const int bn = ((j.nTiles == 2) ? (t & 1) : 0) * 128;

    const int q = tid >> 2;                                   // 0..63
    const int skz = (((tid & 3) ^ ((tid >> 3) & 3)) << 3);    // chunk-XOR swizzle

    int tr0 = bm + q;       if (tr0 > j.M - 1) tr0 = j.M - 1;
    int tr1 = bm + 64 + q;  if (tr1 > j.M - 1) tr1 = j.M - 1;
    size_t aoff0[2], aoff1[2];
    if (G) {
        int g00 = j.ia[j.row0 + tr0], g01 = j.ia[j.row0 + tr1];
        int g10 = j.ib[j.row0 + tr0], g11 = j.ib[j.row0 + tr1];
        aoff0[0] = (size_t)g00 * j.astride + skz;
        aoff1[0] = (size_t)g01 * j.astride + skz;
        aoff0[1] = (size_t)g10 * j.astride + skz;
        aoff1[1] = (size_t)g11 * j.astride + skz;
    } else {
        aoff0[0] = aoff0[1] = (size_t)tr0 * j.astride + skz;
        aoff1[0] = aoff1[1] = (size_t)tr1 * j.astride + skz;
    }
    const size_t boff = (size_t)(bn + q) * j.wstride + skz;
    const size_t ws64 = (size_t)64 * j.wstride;

    auto STAGE_A = [&](int u, int slot) {
        const int a = u / SPP, ks = u % SPP;
        const ushort_t* Ap = j.A[a] + (size_t)ks * 32;
        gl_lds16(Ap + aoff0[a], &Ab[slot][wv * 512]);
        gl_lds16(Ap + aoff1[a], &Ab[slot][2048 + wv * 512]);
    };
    auto STAGE_B = [&](int s2, int slot) {
        const int u = s2 >> 1, a = u / SPP, ks = u % SPP, h = s2 & 1;
        const ushort_t* Bp = (h ? j.Bl[a] : j.Bh[a]) + boff + (size_t)ks * 32;
        gl_lds16(Bp,        &Bb[slot][wv * 512]);
        gl_lds16(Bp + ws64, &Bb[slot][2048 + wv * 512]);
    };

    f32x4 acc[4][4] = {};
    s16x8 a_frag[4];
    const int arow = lane & 15;
    const int k8s = ((lane >> 4) * 8) ^ (((arow >> 1) & 3) << 3);
    const int wrA = (wv >> 1) * 64;
    const int wrB = (wv & 1) * 64;

    constexpr int NS = NA * SPP * 2;
    STAGE_A(0, 0); STAGE_B(0, 0);     // 4 loads (step 0)
    STAGE_B(1, 1);                    // 2 loads (step 1)

#pragma unroll
    for (int s = 0; s < NS; ++s) {
        const int bslot = s % 3;
        __builtin_amdgcn_s_barrier();
        __builtin_amdgcn_sched_barrier(0);
        if (s + 2 < NS) {
            if (((s + 2) & 1) == 0) STAGE_A((s + 2) >> 1, ((s + 2) >> 1) & 1);
            STAGE_B(s + 2, (s + 2) % 3);
        }
        // wait: everything except stages for steps s+1 and s+2
        const int pend = ((s + 1 < NS) ? (((s + 1) & 1) ? 2 : 4) : 0)
                       + ((s + 2 < NS) ? (((s + 2) & 1) ? 2 : 4) : 0);
        if (pend >= 6)      asm volatile("s_waitcnt vmcnt(6)" ::: "memory");
        else if (pend == 4) asm volatile("s_waitcnt vmcnt(4)" ::: "memory");
        else if (pend == 2) asm volatile("s_waitcnt vmcnt(2)" ::: "memory");
        else                asm volatile("s_waitcnt vmcnt(0)" ::: "memory");
        __builtin_amdgcn_sched_barrier(0);

        if ((s & 1) == 0) {
            const int aslot = (s >> 1) & 1;
#pragma unroll
            for (int m = 0; m < 4; ++m)
                a_frag[m] = *(const s16x8*)&Ab[aslot][(wrA + m * 16 + arow) * 32 + k8s];
        }
        __builtin_amdgcn_s_setprio(1);
#pragma unroll
        for (int n = 0; n < 4; ++n) {
            s16x8 b = *(const s16x8*)&Bb[bslot][(wrB + n * 16 + arow) * 32 + k8s];
#pragma unroll
            for (int m = 0; m < 4; ++m)
                acc[m][n] = __builtin_amdgcn_mfma_f32_16x16x32_bf16(a_frag[m], b, acc[m][n], 0, 0, 0);
        }
        __builtin_amdgcn_s_setprio(0);
    }

    // epilogue: C/D layout col=lane&15, row=(lane>>4)*4+jj
    const int colC = lane & 15;
    const int rb = (lane >> 4) * 4;
    if (FC4) {
        if (!(wv & 1)) {        // waves holding cols 0..63
#pragma unroll
            for (int m = 0; m < 4; ++m) {
#pragma unroll
                for (int jj = 0; jj < 4; ++jj) {
                    const int r = bm + wrA + m * 16 + rb + jj;
                    float v = 0.f;
#pragma unroll
                    for (int n = 0; n < 4; ++n) {
                        const int c = n * 16 + colC;
                        float e = acc[m][n][jj] + j.bias[c];
                        e = fmaxf(e, 0.f);
                        v += e * j.w4[c];
                    }
#pragma unroll
                    for (int o = 1; o < 16; o <<= 1) v += __shfl_xor(v, o);
                    if (colC == 0 && r < j.M) j.out1[r] = v + j.b4[0];
                }
            }
        }
    } else {
#pragma unroll
        for (int m = 0; m < 4; ++m) {
#pragma unroll
            for (int jj = 0; jj < 4; ++jj) {
                const int r = bm + wrA + m * 16 + rb + jj;
                if (r < j.M) {
#pragma unroll
                    for (int n = 0; n < 4; ++n) {
                        const int c = bn + wrB + n * 16 + colC;
                        if (c < j.N) {
                            float v = acc[m][n][jj] + j.bias[c];
                            if (j.relu) v = fmaxf(v, 0.f);
                            j.C[(size_t)r * j.N + c] = f2bf(v);
                        }
                    }
                }
            }
        }
    }
}

extern "C" void kernel_launch(void* const* d_in, const int* in_sizes, int n_in,
                              void* d_out, int out_size, void* d_ws, size_t ws_size,
                              hipStream_t stream)
{
    const int*   drug_id   = (const int*)d_in[0];
    const float* disease_x = (const float*)d_in[1];
    const int*   dis_id    = (const int*)d_in[2];
    const int*   e_mt      = (const int*)d_in[3];
    const int*   e_rev     = (const int*)d_in[4];
    const int*   e_lbl     = (const int*)d_in[5];
    const float* drug_emb  = (const float*)d_in[6];
    const float* dis_emb   = (const float*)d_in[7];
    const float* lin_w     = (const float*)d_in[8];
    const float* lin_b     = (const float*)d_in[9];
    const float* Wl_mt     = (const float*)d_in[10];
    const float* bl_mt     = (const float*)d_in[11];
    const float* Wr_mt     = (const float*)d_in[12];
    const float* Wl_rev    = (const float*)d_in[13];
    const float* bl_rev    = (const float*)d_in[14];
    const float* Wr_rev    = (const float*)d_in[15];
    const float* fc1_w = (const float*)d_in[16]; const float* fc1_b = (const float*)d_in[17];
    const float* fc2_w = (const float*)d_in[18]; const float* fc2_b = (const float*)d_in[19];
    const float* fc3_w = (const float*)d_in[20]; const float* fc3_b = (const float*)d_in[21];
    const float* fc4_w = (const float*)d_in[22]; const float* fc4_b = (const float*)d_in[23];
    float* out = (float*)d_out;

    // ---- workspace layout (~106 MB) ----
    char* base = (char*)d_ws;
    size_t o = 0;
    auto alloc = [&](size_t bytes) { char* r = base + o; o += (bytes + 255) & ~(size_t)255; return r; };
    const size_t XB = (size_t)20000 * 256 * 2;   // one bf16 activation plane (exactly 256-aligned)

    ushort_t* x_dis   = (ushort_t*)alloc(XB);
    ushort_t* x_drug  = (ushort_t*)alloc(XB);
    // next 5 planes are contiguous: e1 [100000][256] bf16 aliases them
    ushort_t* y_dis   = (ushort_t*)alloc(XB);
    ushort_t* y_drug  = (ushort_t*)alloc(XB);
    ushort_t* agg_dis = (ushort_t*)alloc(XB);
    ushort_t* agg_drug= (ushort_t*)alloc(XB);
    (void)alloc(XB);                              // extraE: e1 tail
    ushort_t* e2      = (ushort_t*)alloc((size_t)100000 * 128 * 2);
    const size_t WB = (size_t)4 * 256 * 256 * 2;
    ushort_t* wlmt_h  = (ushort_t*)alloc(WB); ushort_t* wlmt_l  = (ushort_t*)alloc(WB);
    ushort_t* wrmt_h  = (ushort_t*)alloc(WB); ushort_t* wrmt_l  = (ushort_t*)alloc(WB);
    ushort_t* wlrev_h = (ushort_t*)alloc(WB); ushort_t* wlrev_l = (ushort_t*)alloc(WB);
    ushort_t* wrrev_h = (ushort_t*)alloc(WB); ushort_t* wrrev_l = (ushort_t*)alloc(WB);
    ushort_t* fc1t_h  = (ushort_t*)alloc(512 * 256 * 2); ushort_t* fc1t_l = (ushort_t*)alloc(512 * 256 * 2);
    ushort_t* fc2t_h  = (ushort_t*)alloc(256 * 128 * 2); ushort_t* fc2t_l = (ushort_t*)alloc(256 * 128 * 2);
    ushort_t* fc3t_h  = (ushort_t*)alloc(128 * 128 * 2); ushort_t* fc3t_l = (ushort_t*)alloc(128 * 128 * 2);
    int* cnts     = (int*)alloc(80000 * 4);
    int* cnt_dis  = cnts;
    int* cnt_drug = cnts + 20000;
    int* cur_dis  = cnts + 40000;
    int* cur_drug = cnts + 60000;
    int* off_dis  = (int*)alloc(20004 * 4);
    int* off_drug = (int*)alloc(20004 * 4);
    int* csr_mt   = (int*)alloc(400000 * 4);
    int* csr_rev  = (int*)alloc(400000 * 4);
    ushort_t* e1 = y_dis;      // [100000][256] bf16, spans 5 planes

    hipMemsetAsync(cnts, 0, 80000 * sizeof(int), stream);
    hipMemsetAsync(fc3t_h, 0, 128 * 128 * 2, stream);
    hipMemsetAsync(fc3t_l, 0, 128 * 128 * 2, stream);

    TP tp;
    tp.src[0] = Wl_mt;  tp.th[0] = wlmt_h;  tp.tl[0] = wlmt_l;
    tp.src[1] = Wr_mt;  tp.th[1] = wrmt_h;  tp.tl[1] = wrmt_l;
    tp.src[2] = Wl_rev; tp.th[2] = wlrev_h; tp.tl[2] = wlrev_l;
    tp.src[3] = Wr_rev; tp.th[3] = wrrev_h; tp.tl[3] = wrrev_l;
    tp.src[4] = fc1_w;  tp.th[4] = fc1t_h;  tp.tl[4] = fc1t_l;
    tp.src[5] = fc2_w;  tp.th[5] = fc2t_h;  tp.tl[5] = fc2t_l;
    tp.src[6] = fc3_w;  tp.th[6] = fc3t_h;  tp.tl[6] = fc3t_l;
    k_trans_all<<<298, 256, 0, stream>>>(tp);

    k_init<<<NDRUG, HID, 0, stream>>>(drug_id, drug_emb, disease_x, lin_w, lin_b,
                                      dis_id, dis_emb, x_drug, x_dis);
    int nbE = (NE + 255) / 256;
    k_count<<<nbE, 256, 0, stream>>>(e_mt + NE, NE, cnt_dis);
    k_count<<<nbE, 256, 0, stream>>>(e_rev + NE, NE, cnt_drug);
    k_scan<<<2, 1024, 0, stream>>>(cnt_dis, off_dis, cnt_drug, off_drug, 20000);
    k_fill<<<nbE, 256, 0, stream>>>(e_mt, e_mt + NE, NE, off_dis, cur_dis, csr_mt);
    k_fill<<<nbE, 256, 0, stream>>>(e_rev, e_rev + NE, NE, off_drug, cur_drug, csr_rev);

    ushort_t *xd = x_dis, *xg = x_drug;
    ushort_t *td = y_dis, *tg = y_drug;
    const int mT = (20000 + 127) / 128;     // 157
    for (int l = 0; l < NLAYERS; ++l) {
        int relu = (l < NLAYERS - 1) ? 1 : 0;
        size_t wo = (size_t)l * 65536;
        k_agg2<<<NDIS + NDRUG, 128, 0, stream>>>(
            (const uint_t*)xg, off_dis, csr_mt, (uint_t*)agg_dis,
            (const uint_t*)xd, off_drug, csr_rev, (uint_t*)agg_drug);
        GJob jd = { { agg_dis, xd }, { wlmt_h + wo, wrmt_h + wo }, { wlmt_l + wo, wrmt_l + wo },
                    nullptr, nullptr, 0, 256, 256, bl_mt + l * HID,
                    NDIS, 256, relu, 2, td, nullptr, nullptr, nullptr };
        GJob jg = { { agg_drug, xg }, { wlrev_h + wo, wrrev_h + wo }, { wlrev_l + wo, wrrev_l + wo },
                    nullptr, nullptr, 0, 256, 256, bl_rev + l * HID,
                    NDRUG, 256, relu, 2, tg, nullptr, nullptr, nullptr };
        k_mgemm<2, 8, 0, 0><<<mT * 4, 256, 0, stream>>>(jd, jg, mT * 2);
        ushort_t* t;
        t = xd; xd = td; td = t;
        t = xg; xg = tg; tg = t;
    }
    // after 4 swaps x* point at the original x planes; y/agg planes are dead

    // classifier: single chunk of all 100000 label edges
    {
        const int Mc = NEL;
        const int mT1 = (Mc + 127) / 128;   // 782
        GJob f1 = { { xg, xd }, { fc1t_h, fc1t_h + 256 }, { fc1t_l, fc1t_l + 256 },
                    e_lbl, e_lbl + NEL, 0, 256, 512, fc1_b,
                    Mc, 256, 1, 2, e1, nullptr, nullptr, nullptr };
        k_mgemm<2, 8, 1, 0><<<mT1 * 2, 256, 0, stream>>>(f1, f1, mT1 * 2);
        GJob f2 = { { e1, nullptr }, { fc2t_h, nullptr }, { fc2t_l, nullptr },
                    nullptr, nullptr, 0, 256, 256, fc2_b,
                    Mc, 128, 1, 1, e2, nullptr, nullptr, nullptr };
        k_mgemm<1, 8, 0, 0><<<mT1, 256, 0, stream>>>(f2, f2, mT1);
        GJob f3 = { { e2, nullptr }, { fc3t_h, nullptr }, { fc3t_l, nullptr },
                    nullptr, nullptr, 0, 128, 128, fc3_b,
                    Mc, 64, 1, 1, nullptr, fc4_w, fc4_b, out };
        k_mgemm<1, 4, 0, 1><<<mT1, 256, 0, stream>>>(f3, f3, mT1);
    }
}